// Round 15
// baseline (617.059 us; speedup 1.0000x reference)
//
#include <hip/hip_runtime.h>
#include <math.h>

#define NN    50000
#define MP    50048    // padded rows (782*64)
#define NEDGE 250000
#define NHOPE 125000
#define ETOT  375000
#define NRELS 500
#define BATCH 65536
#define LB1   6250     // light blocks (8 waves each -> 50000 waves)
#define HBMAX 5769     // max heavy nodes (deg>64): 375000/65

typedef __attribute__((ext_vector_type(8))) short bf16x8;
typedef __attribute__((ext_vector_type(4))) float f32x4;

__device__ __forceinline__ unsigned short bf16rne(float f) {
  unsigned u = __float_as_uint(f);
  unsigned r = (u + 0x7FFFu + ((u >> 16) & 1u)) >> 16;
  return (unsigned short)r;
}
__device__ __forceinline__ float b2f(unsigned short u) {
  return __uint_as_float(((unsigned)u) << 16);
}

struct GJob {
  const unsigned short* A;   // padded rows x KP bf16
  int M;                     // valid rows
  const unsigned short* B;   // 208 x KP bf16
  float* Cf;                 // f32 out (ld 200) or null
  unsigned short* Cbf;       // bf16 out (ld ldcb) or null
  int ldcb;
  const float* a2;           // 200 floats or null
  float* dot;                // per-row scalar(s) or null
  int dotmode;               // 1 = split at 100, 2 = single sum
};

// ---------------- fused: l2norm (y=0) + histk (y=1) + weight conversions (y=2) ----------------
__global__ __launch_bounds__(256) void startk(const float* __restrict__ in,
                                              unsigned short* __restrict__ out,
                                              const int* __restrict__ el, const int* __restrict__ tin,
                                              int* __restrict__ deg,
                                              const float* __restrict__ rel,
                                              const float* __restrict__ ah,
                                              const float* __restrict__ W_ent,
                                              const float* __restrict__ W_gat,
                                              const float* __restrict__ a_out,
                                              unsigned short* __restrict__ B1s,
                                              unsigned short* __restrict__ B1d,
                                              unsigned short* __restrict__ Brel1,
                                              unsigned short* __restrict__ Bxw,
                                              unsigned short* __restrict__ Bwgat,
                                              unsigned short* __restrict__ B2s,
                                              unsigned short* __restrict__ B2d,
                                              unsigned short* __restrict__ B2rel,
                                              unsigned short* __restrict__ relbf) {
  if (blockIdx.y == 1) {
    int i = blockIdx.x * 256 + threadIdx.x;
    if (i < ETOT) {
      int e0 = (i < NEDGE) ? el[i] : tin[(size_t)(i - NEDGE) * 4 + 3];
      atomicAdd(&deg[e0], 1);
    }
    return;
  }
  if (blockIdx.y == 2) {
    const int S1 = 26624, S2 = 46592;   // 208*128, 208*224
    int idx = blockIdx.x * 256 + threadIdx.x;
    if (idx < 3 * S1) {                 // B1s / B1d / Brel1
      int y = idx / S1, r = idx - y * S1;
      int j = r >> 7, k = r & 127;
      float v = 0.f;
      if (j < 200 && k < 100)
        v = ah[((j < 100) ? 0 : 30000) + (j % 100) * 300 + y * 100 + k];
      (y == 0 ? B1s : (y == 1 ? B1d : Brel1))[r] = bf16rne(v);
    } else if (idx < 4 * S1) {          // Bxw : W_ent^T
      int r = idx - 3 * S1;
      int j = r >> 7, k = r & 127;
      float v = (j < 200 && k < 100) ? W_ent[(size_t)k * 200 + j] : 0.f;
      Bxw[r] = bf16rne(v);
    } else if (idx < 5 * S1) {          // Bwgat : W_gat^T
      int r = idx - 4 * S1;
      int j = r >> 7, k = r & 127;
      float v = (j < 200 && k < 100) ? W_gat[(size_t)k * 200 + j] : 0.f;
      Bwgat[r] = bf16rne(v);
    } else if (idx < 5 * S1 + 3 * S2) { // B2s / B2d / B2rel
      int r = idx - 5 * S1;
      int y = r / S2; r -= y * S2;
      int j = r / 224, k = r - j * 224;
      float v = (j < 200 && k < 200) ? a_out[(size_t)j * 600 + y * 200 + k] : 0.f;
      (y == 0 ? B2s : (y == 1 ? B2d : B2rel))[r] = bf16rne(v);
    } else if (idx < 5 * S1 + 3 * S2 + 65536) {  // relbf 512x128
      int r = idx - 5 * S1 - 3 * S2;
      int j = r >> 7, k = r & 127;
      float v = (j < 500 && k < 100) ? rel[(size_t)j * 100 + k] : 0.f;
      relbf[r] = bf16rne(v);
    }
    return;
  }
  int row  = blockIdx.x * 4 + (threadIdx.x >> 6);
  int lane = threadIdx.x & 63;
  if (row >= MP) return;
  unsigned short* o = out + (size_t)row * 128;
  if (row >= NN) { o[lane] = 0; o[lane + 64] = 0; return; }
  const float* r = in + (size_t)row * 100;
  float v0 = r[lane];
  float v1 = (lane + 64 < 100) ? r[lane + 64] : 0.f;
  float ss = v0 * v0 + v1 * v1;
  #pragma unroll
  for (int off = 1; off < 64; off <<= 1) ss += __shfl_xor(ss, off);
  float inv = 1.f / fmaxf(sqrtf(ss), 1e-12f);
  o[lane] = bf16rne(v0 * inv);
  o[lane + 64] = (lane + 64 < 100) ? bf16rne(v1 * inv) : (unsigned short)0;
}

// ---------------- multi-job bf16 MFMA GEMM, LDS-staged B, LDS-coalesced epilogue ----------------
template<int KP>
__global__ __launch_bounds__(256) void gemm_multi(GJob j0, GJob j1, GJob j2, GJob j3, GJob j4) {
  __shared__ __attribute__((aligned(16))) char smem[54272];
  unsigned short* shb = (unsigned short*)smem;
  float (*clds)[16][212] = (float (*)[16][212])smem;   // [4][16][212]
  GJob jb = (blockIdx.y == 0) ? j0 : (blockIdx.y == 1) ? j1 : (blockIdx.y == 2) ? j2
          : (blockIdx.y == 3) ? j3 : j4;
  if (blockIdx.x * 64 >= jb.M) return;
  int wv = threadIdx.x >> 6, lane = threadIdx.x & 63;
  int rbw = blockIdx.x * 64 + wv * 16;
  int rl = lane & 15;
  int kq = (lane >> 4) * 8;
  const unsigned short* ap = jb.A + (size_t)(rbw + rl) * KP + kq;
  f32x4 acc[13];
  #pragma unroll
  for (int t = 0; t < 13; ++t) acc[t] = (f32x4){0.f, 0.f, 0.f, 0.f};
  constexpr int NST = (KP + 63) / 64;
  #pragma unroll
  for (int s = 0; s < NST; ++s) {
    const int ks0 = s * 64;
    const int sw  = (KP - ks0 >= 64) ? 64 : (KP - ks0);
    const int cpr = sw / 8;
    __syncthreads();
    for (int idx = threadIdx.x; idx < 208 * cpr; idx += 256) {
      int row = idx / cpr, cw = idx - row * cpr;
      *(float4*)(shb + row * 72 + cw * 8) =
          *(const float4*)(jb.B + (size_t)row * KP + ks0 + cw * 8);
    }
    __syncthreads();
    for (int ksl = 0; ksl < sw; ksl += 32) {
      bf16x8 a0 = *(const bf16x8*)(ap + ks0 + ksl);
      const unsigned short* bl = shb + (size_t)rl * 72 + kq + ksl;
      #pragma unroll
      for (int t = 0; t < 13; ++t) {
        bf16x8 b = *(const bf16x8*)(bl + t * 16 * 72);
        acc[t] = __builtin_amdgcn_mfma_f32_16x16x32_bf16(a0, b, acc[t], 0, 0, 0);
      }
    }
  }
  int rg = (lane >> 4) * 4;
  if (jb.dot) {
    float p0[4] = {0.f, 0.f, 0.f, 0.f}, p1[4] = {0.f, 0.f, 0.f, 0.f};
    #pragma unroll
    for (int t = 0; t < 13; ++t) {
      int col = t * 16 + rl;
      float av = (col < 200) ? jb.a2[col] : 0.f;
      bool lo = (col < 100);
      #pragma unroll
      for (int g = 0; g < 4; ++g) {
        float v = acc[t][g] * av;
        if (lo) p0[g] += v; else p1[g] += v;
      }
    }
    #pragma unroll
    for (int off = 1; off < 16; off <<= 1) {
      #pragma unroll
      for (int g = 0; g < 4; ++g) {
        p0[g] += __shfl_xor(p0[g], off);
        p1[g] += __shfl_xor(p1[g], off);
      }
    }
    if (rl == 0) {
      #pragma unroll
      for (int g = 0; g < 4; ++g) {
        int row = rbw + rg + g;
        if (row < jb.M) {
          if (jb.dotmode == 1) { jb.dot[row * 2] = p0[g]; jb.dot[row * 2 + 1] = p1[g]; }
          else                 { jb.dot[row] = p0[g] + p1[g]; }
        }
      }
    }
  }
  if (jb.Cf || jb.Cbf) {
    __syncthreads();
    #pragma unroll
    for (int t = 0; t < 13; ++t) {
      #pragma unroll
      for (int g = 0; g < 4; ++g)
        clds[wv][rg + g][t * 16 + rl] = acc[t][g];
    }
    __syncthreads();
    #pragma unroll
    for (int i = 0; i < 13; ++i) {
      int idx = i * 64 + lane;
      if (idx < 800) {
        int r = idx / 50, cw = idx - r * 50;
        float4 v = *(const float4*)&clds[wv][r][cw * 4];
        int grow = rbw + r;
        if (grow < jb.M) {
          if (jb.Cf)
            *(float4*)(jb.Cf + (size_t)grow * 200 + cw * 4) = v;
          if (jb.Cbf) {
            ushort4 o = {bf16rne(v.x), bf16rne(v.y), bf16rne(v.z), bf16rne(v.w)};
            *(ushort4*)(jb.Cbf + (size_t)grow * jb.ldcb + cw * 4) = o;
          }
        }
      }
    }
  }
}

// ---------------- CSR scans ----------------
__global__ __launch_bounds__(256) void scanA(const int* __restrict__ deg, int* __restrict__ bsum, int n) {
  __shared__ int s[256];
  int t = threadIdx.x;
  int i = blockIdx.x * 256 + t;
  s[t] = (i < n) ? deg[i] : 0;
  __syncthreads();
  for (int off = 128; off > 0; off >>= 1) {
    if (t < off) s[t] += s[t + off];
    __syncthreads();
  }
  if (t == 0) bsum[blockIdx.x] = s[0];
}

// scanC with inline bsum prefix + light-degree histogram
__global__ __launch_bounds__(256) void scanC(const int* __restrict__ deg, const int* __restrict__ bsum,
                                             int* __restrict__ offs, int* __restrict__ pos,
                                             int* __restrict__ dhist, int n, int total) {
  __shared__ int sb[256];
  __shared__ int s[256];
  int t = threadIdx.x;
  sb[t] = (t < 196) ? bsum[t] : 0;
  __syncthreads();
  for (int off = 1; off < 256; off <<= 1) {
    int add = (t >= off) ? sb[t - off] : 0;
    __syncthreads();
    sb[t] += add;
    __syncthreads();
  }
  int base = (blockIdx.x == 0) ? 0 : sb[blockIdx.x - 1];
  int i = blockIdx.x * 256 + t;
  int v = (i < n) ? deg[i] : 0;
  s[t] = v;
  __syncthreads();
  for (int off = 1; off < 256; off <<= 1) {
    int add = (t >= off) ? s[t - off] : 0;
    __syncthreads();
    s[t] += add;
    __syncthreads();
  }
  if (i < n) {
    int e = base + s[t] - v;
    offs[i] = e;
    pos[i]  = e;
    if (v <= 64) atomicAdd(&dhist[v], 1);
  }
  if (i == 0) offs[n] = total;
}

// fused: scatterk (y=0) + degree-bucketed buildLists (y=1)
__global__ __launch_bounds__(256) void scatBuild(const int* __restrict__ el, const int* __restrict__ et,
                                                 const int* __restrict__ tin, const int* __restrict__ offs,
                                                 int* __restrict__ pos, int2* __restrict__ edata,
                                                 int* __restrict__ lightL, int* __restrict__ heavyL,
                                                 int* __restrict__ cnts,
                                                 const int* __restrict__ dhist, int* __restrict__ dpos) {
  __shared__ int dpre[65];
  if (blockIdx.y == 0) {
    int i = blockIdx.x * 256 + threadIdx.x;
    if (i >= ETOT) return;
    int e0, e1, t1, t2f;
    if (i < NEDGE) {
      e0 = el[i]; e1 = el[NEDGE + i]; t1 = et[i]; t2f = 0;
    } else {
      const int* q = tin + (size_t)(i - NEDGE) * 4;
      e0 = q[3]; e1 = q[0]; t1 = q[1]; t2f = q[2] + 1;
    }
    int slot = atomicAdd(&pos[e0], 1);
    edata[slot] = make_int2(e1 | (t1 << 16), t2f | (e0 << 9));
    return;
  }
  if (threadIdx.x == 0) {
    int acc = 0;
    for (int d = 0; d <= 64; ++d) { dpre[d] = acc; acc += dhist[d]; }
  }
  __syncthreads();
  int i = blockIdx.x * 256 + threadIdx.x;
  int lane = threadIdx.x & 63;
  bool valid = (i < NN);
  int d = valid ? (offs[i + 1] - offs[i]) : -1;
  bool heavy = valid && (d > 64);
  bool light = valid && (d >= 0 && d <= 64);
  unsigned long long below = (1ULL << lane) - 1ULL;
  // heavy: wave-aggregated append
  unsigned long long mh = __ballot(heavy);
  int bh = 0;
  if (lane == 0 && mh) bh = atomicAdd(&cnts[1], __popcll(mh));
  bh = __shfl(bh, 0);
  if (heavy) heavyL[bh + __popcll(mh & below)] = i;
  // light count (for gather bounds)
  unsigned long long ml = __ballot(light);
  if (lane == 0 && ml) atomicAdd(&cnts[0], __popcll(ml));
  // light: degree-bucketed scatter, ballot-grouped per (wave, degree)
  unsigned long long remaining = ml;
  while (remaining) {
    int leader = __ffsll((unsigned long long)remaining) - 1;
    int dl = __shfl(d, leader);
    unsigned long long grp = __ballot(light && d == dl);
    int bse = 0;
    if (lane == leader) bse = atomicAdd(&dpos[dl], __popcll(grp));
    bse = __shfl(bse, leader);
    if (light && d == dl) lightL[dpre[dl] + bse + __popcll(grp & below)] = i;
    remaining &= ~grp;
  }
}

// ---------------- fused: edgeEE1 (y=0) + padx/maskset (y=1) ----------------
__global__ __launch_bounds__(256) void eeMisc1(const int2* __restrict__ edata,
                                               const float* __restrict__ ssrc,
                                               const float* __restrict__ sdst,
                                               const float* __restrict__ srel,
                                               float2* __restrict__ ee,
                                               unsigned short* __restrict__ xbf,
                                               const int* __restrict__ bi,
                                               float* __restrict__ maskA) {
  if (blockIdx.y == 1) {
    if (blockIdx.x < 42) {
      int i = blockIdx.x * 256 + threadIdx.x;
      if (i < (MP - NN) * 224) xbf[(size_t)NN * 224 + i] = 0;
    } else if (blockIdx.x < 42 + 256) {
      int t = (blockIdx.x - 42) * 256 + threadIdx.x;
      if (t < BATCH) maskA[bi[t * 3 + 2]] = 1.0f;
    }
    return;
  }
  int q = blockIdx.x * 256 + threadIdx.x;
  if (q >= ETOT) return;
  int2 ed = edata[q];
  int e1 = ed.x & 0xFFFF;
  int t1 = ((unsigned)ed.x) >> 16;
  int t2f = ed.y & 0x1FF;
  int e0 = ((unsigned)ed.y) >> 9;
  float p0 = ssrc[e0 * 2]     + sdst[e1 * 2]     + srel[t1 * 2];
  float p1 = ssrc[e0 * 2 + 1] + sdst[e1 * 2 + 1] + srel[t1 * 2 + 1];
  if (t2f) { int t2 = t2f - 1; p0 += srel[t2 * 2]; p1 += srel[t2 * 2 + 1]; }
  p0 = (p0 > 0.f) ? p0 : 0.2f * p0;
  p1 = (p1 > 0.f) ? p1 : 0.2f * p1;
  ee[q] = make_float2(__expf(-p0), __expf(-p1));
}

__global__ __launch_bounds__(256) void edgeEE2(const int2* __restrict__ edata,
                                               const float* __restrict__ ssrc,
                                               const float* __restrict__ sdst,
                                               const float* __restrict__ srel,
                                               float* __restrict__ ee) {
  int q = blockIdx.x * 256 + threadIdx.x;
  if (q >= ETOT) return;
  int2 ed = edata[q];
  int e1 = ed.x & 0xFFFF;
  int t1 = ((unsigned)ed.x) >> 16;
  int t2f = ed.y & 0x1FF;
  int e0 = ((unsigned)ed.y) >> 9;
  float p = ssrc[e0] + sdst[e1] + srel[t1];
  if (t2f) p += srel[t2f - 1];
  p = (p > 0.f) ? p : 0.2f * p;
  ee[q] = __expf(-p);
}

// ---------------- merged layer-1 gather ----------------
__global__ __launch_bounds__(512) void gather1M(const int* __restrict__ lightL, const int* __restrict__ heavyL,
    const int* __restrict__ cnts, const int* __restrict__ offs, const int2* __restrict__ edata,
    const float2* __restrict__ eeb,
    const unsigned short* __restrict__ srcb, const unsigned short* __restrict__ dstb,
    const unsigned short* __restrict__ relpb,
    unsigned short* __restrict__ xbf) {
  __shared__ float part[8][208];
  int w = threadIdx.x >> 6, lane = threadIdx.x & 63;
  bool act = lane < 50;
  int cb = lane * 4;
  float a0 = 0.f, a1 = 0.f, a2v = 0.f, a3 = 0.f, rs0 = 0.f, rs1 = 0.f;
  bool hd0 = (cb < 100);
  auto edgeop = [&](int2 ed, float2 ev) {
    int e1 = ed.x & 0xFFFF;
    int t1 = ((unsigned)ed.x) >> 16;
    int t2f = ed.y & 0x1FF;
    rs0 += ev.x; rs1 += ev.y;
    if (act) {
      ushort4 dv = *(const ushort4*)(dstb + (size_t)e1 * 200 + cb);
      ushort4 rv = *(const ushort4*)(relpb + (size_t)t1 * 200 + cb);
      float m0 = b2f(dv.x) + b2f(rv.x);
      float m1 = b2f(dv.y) + b2f(rv.y);
      float m2 = b2f(dv.z) + b2f(rv.z);
      float m3 = b2f(dv.w) + b2f(rv.w);
      if (t2f) {
        ushort4 r2 = *(const ushort4*)(relpb + (size_t)(t2f - 1) * 200 + cb);
        m0 += b2f(r2.x); m1 += b2f(r2.y); m2 += b2f(r2.z); m3 += b2f(r2.w);
      }
      float ee = hd0 ? ev.x : ev.y;
      a0 += ee * m0; a1 += ee * m1; a2v += ee * m2; a3 += ee * m3;
    }
  };
  if (blockIdx.x < HBMAX) {
    int hidx = blockIdx.x;
    if (hidx >= cnts[1]) return;
    int node = heavyL[hidx];
    int s = offs[node], e = offs[node + 1];
    int q = s + w;
    for (; q + 8 < e; q += 16) { edgeop(edata[q], eeb[q]); edgeop(edata[q + 8], eeb[q + 8]); }
    if (q < e) edgeop(edata[q], eeb[q]);
    if (act) { part[w][cb] = a0; part[w][cb + 1] = a1; part[w][cb + 2] = a2v; part[w][cb + 3] = a3; }
    if (lane == 0) { part[w][200] = rs0; part[w][201] = rs1; }
    __syncthreads();
    int t = threadIdx.x;
    if (t < 224) {
      unsigned short outv = 0;
      if (t < 200) {
        float a = 0.f, r0 = 0.f, r1 = 0.f;
        #pragma unroll
        for (int wv = 0; wv < 8; ++wv) { a += part[wv][t]; r0 += part[wv][200]; r1 += part[wv][201]; }
        float inv = (t < 100) ? 1.f / r0 : 1.f / r1;
        float v = b2f(srcb[(size_t)node * 200 + t]) + a * inv;
        v = (v > 0.f) ? v : expm1f(v);
        outv = bf16rne(v);
      }
      xbf[(size_t)node * 224 + t] = outv;
    }
    return;
  }
  int widx = (blockIdx.x - HBMAX) * 8 + w;
  if (widx >= cnts[0]) return;
  int node = lightL[widx];
  int s = offs[node], e = offs[node + 1];
  int q = s;
  for (; q + 1 < e; q += 2) { edgeop(edata[q], eeb[q]); edgeop(edata[q + 1], eeb[q + 1]); }
  if (q < e) edgeop(edata[q], eeb[q]);
  bool has = (e > s);
  unsigned short* xo = xbf + (size_t)node * 224;
  if (act) {
    float inv = has ? (hd0 ? 1.f / rs0 : 1.f / rs1) : 0.f;
    ushort4 sv = *(const ushort4*)(srcb + (size_t)node * 200 + cb);
    float v0 = has ? b2f(sv.x) + a0 * inv : 0.f;
    float v1 = has ? b2f(sv.y) + a1 * inv : 0.f;
    float v2 = has ? b2f(sv.z) + a2v * inv : 0.f;
    float v3 = has ? b2f(sv.w) + a3 * inv : 0.f;
    v0 = (v0 > 0.f) ? v0 : expm1f(v0);
    v1 = (v1 > 0.f) ? v1 : expm1f(v1);
    v2 = (v2 > 0.f) ? v2 : expm1f(v2);
    v3 = (v3 > 0.f) ? v3 : expm1f(v3);
    ushort4 ov = {bf16rne(v0), bf16rne(v1), bf16rne(v2), bf16rne(v3)};
    *(ushort4*)(xo + cb) = ov;
  } else if (lane < 56) {
    ushort4 z = {0, 0, 0, 0};
    *(ushort4*)(xo + cb) = z;
  }
}

// ---------------- merged layer-2 gather with FUSED final (elu + mask + l2norm -> out) ----------------
__global__ __launch_bounds__(512) void gather2M(const int* __restrict__ lightL, const int* __restrict__ heavyL,
    const int* __restrict__ cnts, const int* __restrict__ offs, const int2* __restrict__ edata,
    const float* __restrict__ eeb,
    const unsigned short* __restrict__ srcb, const unsigned short* __restrict__ dstb,
    const unsigned short* __restrict__ relpb,
    const unsigned short* __restrict__ xwb,
    const float* __restrict__ maskA, float* __restrict__ out) {
  __shared__ float part[8][208];
  __shared__ float red[512];
  int w = threadIdx.x >> 6, lane = threadIdx.x & 63;
  bool act = lane < 50;
  int cb = lane * 4;
  float a0 = 0.f, a1 = 0.f, a2v = 0.f, a3 = 0.f, rs = 0.f;
  auto edgeop = [&](int2 ed, float ee) {
    int e1 = ed.x & 0xFFFF;
    int t1 = ((unsigned)ed.x) >> 16;
    int t2f = ed.y & 0x1FF;
    rs += ee;
    if (act) {
      ushort4 dv = *(const ushort4*)(dstb + (size_t)e1 * 200 + cb);
      ushort4 rv = *(const ushort4*)(relpb + (size_t)t1 * 200 + cb);
      float m0 = b2f(dv.x) + b2f(rv.x);
      float m1 = b2f(dv.y) + b2f(rv.y);
      float m2 = b2f(dv.z) + b2f(rv.z);
      float m3 = b2f(dv.w) + b2f(rv.w);
      if (t2f) {
        ushort4 r2 = *(const ushort4*)(relpb + (size_t)(t2f - 1) * 200 + cb);
        m0 += b2f(r2.x); m1 += b2f(r2.y); m2 += b2f(r2.z); m3 += b2f(r2.w);
      }
      a0 += ee * m0; a1 += ee * m1; a2v += ee * m2; a3 += ee * m3;
    }
  };
  if (blockIdx.x < HBMAX) {
    int hidx = blockIdx.x;
    if (hidx >= cnts[1]) return;
    int node = heavyL[hidx];
    int s = offs[node], e = offs[node + 1];
    int q = s + w;
    for (; q + 8 < e; q += 16) { edgeop(edata[q], eeb[q]); edgeop(edata[q + 8], eeb[q + 8]); }
    if (q < e) edgeop(edata[q], eeb[q]);
    if (act) { part[w][cb] = a0; part[w][cb + 1] = a1; part[w][cb + 2] = a2v; part[w][cb + 3] = a3; }
    if (lane == 0) part[w][200] = rs;
    __syncthreads();
    int t = threadIdx.x;
    float m = maskA[node];
    float u = 0.f;
    if (t < 200) {
      float a = 0.f, r = 0.f;
      #pragma unroll
      for (int wv = 0; wv < 8; ++wv) { a += part[wv][t]; r += part[wv][200]; }
      float v = b2f(srcb[(size_t)node * 200 + t]) + a / r;
      v = (v > 0.f) ? v : expm1f(v);
      u = b2f(xwb[(size_t)node * 200 + t]) + m * v;
    }
    red[t] = u * u;
    __syncthreads();
    #pragma unroll
    for (int off = 256; off > 0; off >>= 1) {
      if (t < off) red[t] += red[t + off];
      __syncthreads();
    }
    float inv = 1.f / fmaxf(sqrtf(red[0]), 1e-12f);
    if (t < 200) out[(size_t)node * 200 + t] = u * inv;
    return;
  }
  int widx = (blockIdx.x - HBMAX) * 8 + w;
  if (widx >= cnts[0]) return;
  int node = lightL[widx];
  int s = offs[node], e = offs[node + 1];
  int q = s;
  for (; q + 1 < e; q += 2) { edgeop(edata[q], eeb[q]); edgeop(edata[q + 1], eeb[q + 1]); }
  if (q < e) edgeop(edata[q], eeb[q]);
  bool has = (e > s);
  float m = maskA[node];
  float u0 = 0.f, u1 = 0.f, u2 = 0.f, u3 = 0.f;
  if (act) {
    float inv = has ? 1.f / rs : 0.f;
    ushort4 sv = *(const ushort4*)(srcb + (size_t)node * 200 + cb);
    float v0 = has ? b2f(sv.x) + a0 * inv : 0.f;
    float v1 = has ? b2f(sv.y) + a1 * inv : 0.f;
    float v2 = has ? b2f(sv.z) + a2v * inv : 0.f;
    float v3 = has ? b2f(sv.w) + a3 * inv : 0.f;
    v0 = (v0 > 0.f) ? v0 : expm1f(v0);
    v1 = (v1 > 0.f) ? v1 : expm1f(v1);
    v2 = (v2 > 0.f) ? v2 : expm1f(v2);
    v3 = (v3 > 0.f) ? v3 : expm1f(v3);
    ushort4 xv = *(const ushort4*)(xwb + (size_t)node * 200 + cb);
    u0 = b2f(xv.x) + m * v0;
    u1 = b2f(xv.y) + m * v1;
    u2 = b2f(xv.z) + m * v2;
    u3 = b2f(xv.w) + m * v3;
  }
  float ss = u0 * u0 + u1 * u1 + u2 * u2 + u3 * u3;
  #pragma unroll
  for (int off = 1; off < 64; off <<= 1) ss += __shfl_xor(ss, off);
  float inv = 1.f / fmaxf(sqrtf(ss), 1e-12f);
  if (act) {
    float4 ov = {u0 * inv, u1 * inv, u2 * inv, u3 * inv};
    *(float4*)(out + (size_t)node * 200 + cb) = ov;
  }
}

extern "C" void kernel_launch(void* const* d_in, const int* in_sizes, int n_in,
                              void* d_out, int out_size, void* d_ws, size_t ws_size,
                              hipStream_t stream) {
  (void)in_sizes; (void)n_in; (void)out_size; (void)ws_size;
  const float* ent      = (const float*)d_in[0];
  const float* rel      = (const float*)d_in[1];
  const float* a_heads  = (const float*)d_in[3];
  const float* a2_heads = (const float*)d_in[4];
  const float* W_gat    = (const float*)d_in[5];
  const float* a_out    = (const float*)d_in[6];
  const float* a2_out   = (const float*)d_in[7];
  const float* W_ent    = (const float*)d_in[8];
  const int* edge_list  = (const int*)d_in[9];
  const int* edge_type  = (const int*)d_in[10];
  const int* tin        = (const int*)d_in[11];
  const int* binp       = (const int*)d_in[12];

  float* out    = (float*)d_out;
  float* outrel = out + 10000000;     // (500,200) output 1

  float* ws = (float*)d_ws;
  unsigned short* bufSb  = (unsigned short*)ws;                // NN*200 bf16
  unsigned short* dstD   = (unsigned short*)(ws + 5000000);
  unsigned short* relp1b = (unsigned short*)(ws + 10000000);
  unsigned short* relp2b = (unsigned short*)(ws + 10050000);
  float* ssrc1 = ws + 10100000;
  float* sdst1 = ws + 10200000;
  float* s2src = ws + 10300000;
  float* s2dst = ws + 10350000;
  float* srel1 = ws + 10400000;
  float* s2rel = ws + 10402000;
  // ---- contiguous zero region ----
  float* maskA = ws + 10404000;                                 // 50k f32
  int*   deg   = (int*)(ws + 10454000);                         // 50k int
  int*   cnts  = (int*)(ws + 10504000);                         // 8 int
  int*   dhist = (int*)(ws + 10504008);                         // 65 int
  int*   dpos  = (int*)(ws + 10504080);                         // 65 int
  unsigned short* orelb = (unsigned short*)(ws + 10504152);     // 512*224 ushort
  // zero region ends at ws + 10561496
  unsigned short* x0nbf = (unsigned short*)(ws + 10570000);     // MP*128
  unsigned short* xbf   = (unsigned short*)(ws + 13780000);     // MP*224
  unsigned short* B1s   = (unsigned short*)(ws + 19390000);
  unsigned short* B1d   = (unsigned short*)(ws + 19405000);
  unsigned short* Brel1 = (unsigned short*)(ws + 19420000);
  unsigned short* Bxw   = (unsigned short*)(ws + 19435000);
  unsigned short* Bwgat = (unsigned short*)(ws + 19450000);
  unsigned short* B2s   = (unsigned short*)(ws + 19465000);
  unsigned short* B2d   = (unsigned short*)(ws + 19490000);
  unsigned short* B2rel = (unsigned short*)(ws + 19515000);
  unsigned short* relbf = (unsigned short*)(ws + 19540000);     // 512*128
  float2* eeb1 = (float2*)(ws + 19580000);                      // ETOT float2
  float*  eeb2 = ws + 20330000;                                 // ETOT float
  unsigned short* xwb = (unsigned short*)(ws + 20710000);       // NN*200 bf16
  int* ibase  = (int*)(ws + 25710000);
  int* offs   = ibase;                 // 50k+1
  int* pos    = ibase + 50016;
  int* bsum   = ibase + 100016;        // 256
  int* lightL = ibase + 100288;
  int* heavyL = ibase + 150288;
  int2* edata = (int2*)(ibase + 200288);

  hipMemsetAsync(maskA, 0, (size_t)(10561496 - 10404000) * 4, stream);

  // l2norm + histk + weight conversions
  {
    dim3 g(12512, 3);
    startk<<<g, 256, 0, stream>>>(ent, x0nbf, edge_list, tin, deg,
                                  rel, a_heads, W_ent, W_gat, a_out,
                                  B1s, B1d, Brel1, Bxw, Bwgat, B2s, B2d, B2rel, relbf);
  }
  scanA<<<196, 256, 0, stream>>>(deg, bsum, NN);
  scanC<<<196, 256, 0, stream>>>(deg, bsum, offs, pos, dhist, NN, ETOT);
  {
    dim3 g(1465, 2);
    scatBuild<<<g, 256, 0, stream>>>(edge_list, edge_type, tin, offs, pos, edata,
                                     lightL, heavyL, cnts, dhist, dpos);
  }

  // layer-1 projections + xw(bf16) + rel projections + out_relation_1, one 5-job launch
  {
    GJob js    = {x0nbf, NN,    B1s,   nullptr, bufSb,  200, a2_heads, ssrc1, 1};
    GJob jd    = {x0nbf, NN,    B1d,   nullptr, dstD,   200, a2_heads, sdst1, 1};
    GJob jx    = {x0nbf, NN,    Bxw,   nullptr, xwb,    200, nullptr,  nullptr, 0};
    GJob jrel1 = {relbf, NRELS, Brel1, nullptr, relp1b, 200, a2_heads, srel1, 1};
    GJob jorel = {relbf, NRELS, Bwgat, outrel,  orelb,  224, nullptr,  nullptr, 0};
    dim3 g(782, 5);
    gemm_multi<128><<<g, 256, 0, stream>>>(js, jd, jx, jrel1, jorel);
  }

  // edgeEE1 + padx + maskset
  {
    dim3 g(1465, 2);
    eeMisc1<<<g, 256, 0, stream>>>(edata, ssrc1, sdst1, srel1, eeb1, xbf, binp, maskA);
  }

  gather1M<<<HBMAX + LB1, 512, 0, stream>>>(lightL, heavyL, cnts, offs, edata, eeb1,
                                            bufSb, dstD, relp1b, xbf);

  // layer-2 projections + relp2, one 3-job launch
  {
    GJob js    = {xbf,   NN,    B2s,   nullptr, bufSb,  200, a2_out, s2src, 2};
    GJob jd    = {xbf,   NN,    B2d,   nullptr, dstD,   200, a2_out, s2dst, 2};
    GJob jrp2  = {orelb, NRELS, B2rel, nullptr, relp2b, 200, a2_out, s2rel, 2};
    GJob jz    = {nullptr, 0, nullptr, nullptr, nullptr, 0, nullptr, nullptr, 0};
    dim3 g(782, 3);
    gemm_multi<224><<<g, 256, 0, stream>>>(js, jd, jrp2, jz, jz);
  }

  edgeEE2<<<(ETOT + 255) / 256, 256, 0, stream>>>(edata, s2src, s2dst, s2rel, eeb2);

  // gather2 with fused elu+mask+l2norm epilogue -> out
  gather2M<<<HBMAX + LB1, 512, 0, stream>>>(lightL, heavyL, cnts, offs, edata, eeb2,
                                            bufSb, dstD, relp2b, xwb, maskA, out);
}

// Round 16
// 427.269 us; speedup vs baseline: 1.4442x; 1.4442x over previous
//
#include <hip/hip_runtime.h>
#include <math.h>

#define NN    50000
#define MP    50048    // padded rows (782*64)
#define NEDGE 250000
#define NHOPE 125000
#define ETOT  375000
#define NRELS 500
#define BATCH 65536
#define LB1   6250     // light blocks (8 waves each -> 50000 waves)
#define HBMAX 5769     // max heavy nodes (deg>64): 375000/65

typedef __attribute__((ext_vector_type(8))) short bf16x8;
typedef __attribute__((ext_vector_type(4))) float f32x4;

__device__ __forceinline__ unsigned short bf16rne(float f) {
  unsigned u = __float_as_uint(f);
  unsigned r = (u + 0x7FFFu + ((u >> 16) & 1u)) >> 16;
  return (unsigned short)r;
}
__device__ __forceinline__ float b2f(unsigned short u) {
  return __uint_as_float(((unsigned)u) << 16);
}

struct GJob {
  const unsigned short* A;   // padded rows x KP bf16
  int M;                     // valid rows
  const unsigned short* B;   // 208 x KP bf16
  float* Cf;                 // f32 out (ld 200) or null
  unsigned short* Cbf;       // bf16 out (ld ldcb) or null
  int ldcb;
  const float* a2;           // 200 floats or null
  float* dot;                // per-row scalar(s) or null
  int dotmode;               // 1 = split at 100, 2 = single sum
};

// ---------------- fused: l2norm (y=0) + histk (y=1) + weight conversions (y=2) ----------------
__global__ __launch_bounds__(256) void startk(const float* __restrict__ in,
                                              unsigned short* __restrict__ out,
                                              const int* __restrict__ el, const int* __restrict__ tin,
                                              int* __restrict__ deg,
                                              const float* __restrict__ rel,
                                              const float* __restrict__ ah,
                                              const float* __restrict__ W_ent,
                                              const float* __restrict__ W_gat,
                                              const float* __restrict__ a_out,
                                              unsigned short* __restrict__ B1s,
                                              unsigned short* __restrict__ B1d,
                                              unsigned short* __restrict__ Brel1,
                                              unsigned short* __restrict__ Bxw,
                                              unsigned short* __restrict__ Bwgat,
                                              unsigned short* __restrict__ B2s,
                                              unsigned short* __restrict__ B2d,
                                              unsigned short* __restrict__ B2rel,
                                              unsigned short* __restrict__ relbf) {
  if (blockIdx.y == 1) {
    int i = blockIdx.x * 256 + threadIdx.x;
    if (i < ETOT) {
      int e0 = (i < NEDGE) ? el[i] : tin[(size_t)(i - NEDGE) * 4 + 3];
      atomicAdd(&deg[e0], 1);
    }
    return;
  }
  if (blockIdx.y == 2) {
    const int S1 = 26624, S2 = 46592;   // 208*128, 208*224
    int idx = blockIdx.x * 256 + threadIdx.x;
    if (idx < 3 * S1) {                 // B1s / B1d / Brel1
      int y = idx / S1, r = idx - y * S1;
      int j = r >> 7, k = r & 127;
      float v = 0.f;
      if (j < 200 && k < 100)
        v = ah[((j < 100) ? 0 : 30000) + (j % 100) * 300 + y * 100 + k];
      (y == 0 ? B1s : (y == 1 ? B1d : Brel1))[r] = bf16rne(v);
    } else if (idx < 4 * S1) {          // Bxw : W_ent^T
      int r = idx - 3 * S1;
      int j = r >> 7, k = r & 127;
      float v = (j < 200 && k < 100) ? W_ent[(size_t)k * 200 + j] : 0.f;
      Bxw[r] = bf16rne(v);
    } else if (idx < 5 * S1) {          // Bwgat : W_gat^T
      int r = idx - 4 * S1;
      int j = r >> 7, k = r & 127;
      float v = (j < 200 && k < 100) ? W_gat[(size_t)k * 200 + j] : 0.f;
      Bwgat[r] = bf16rne(v);
    } else if (idx < 5 * S1 + 3 * S2) { // B2s / B2d / B2rel
      int r = idx - 5 * S1;
      int y = r / S2; r -= y * S2;
      int j = r / 224, k = r - j * 224;
      float v = (j < 200 && k < 200) ? a_out[(size_t)j * 600 + y * 200 + k] : 0.f;
      (y == 0 ? B2s : (y == 1 ? B2d : B2rel))[r] = bf16rne(v);
    } else if (idx < 5 * S1 + 3 * S2 + 65536) {  // relbf 512x128
      int r = idx - 5 * S1 - 3 * S2;
      int j = r >> 7, k = r & 127;
      float v = (j < 500 && k < 100) ? rel[(size_t)j * 100 + k] : 0.f;
      relbf[r] = bf16rne(v);
    }
    return;
  }
  int row  = blockIdx.x * 4 + (threadIdx.x >> 6);
  int lane = threadIdx.x & 63;
  if (row >= MP) return;
  unsigned short* o = out + (size_t)row * 128;
  if (row >= NN) { o[lane] = 0; o[lane + 64] = 0; return; }
  const float* r = in + (size_t)row * 100;
  float v0 = r[lane];
  float v1 = (lane + 64 < 100) ? r[lane + 64] : 0.f;
  float ss = v0 * v0 + v1 * v1;
  #pragma unroll
  for (int off = 1; off < 64; off <<= 1) ss += __shfl_xor(ss, off);
  float inv = 1.f / fmaxf(sqrtf(ss), 1e-12f);
  o[lane] = bf16rne(v0 * inv);
  o[lane + 64] = (lane + 64 < 100) ? bf16rne(v1 * inv) : (unsigned short)0;
}

// ---------------- multi-job bf16 MFMA GEMM, LDS-staged B, LDS-coalesced epilogue ----------------
template<int KP>
__global__ __launch_bounds__(256) void gemm_multi(GJob j0, GJob j1, GJob j2, GJob j3, GJob j4) {
  __shared__ __attribute__((aligned(16))) char smem[54272];
  unsigned short* shb = (unsigned short*)smem;
  float (*clds)[16][212] = (float (*)[16][212])smem;   // [4][16][212]
  GJob jb = (blockIdx.y == 0) ? j0 : (blockIdx.y == 1) ? j1 : (blockIdx.y == 2) ? j2
          : (blockIdx.y == 3) ? j3 : j4;
  if (blockIdx.x * 64 >= jb.M) return;
  int wv = threadIdx.x >> 6, lane = threadIdx.x & 63;
  int rbw = blockIdx.x * 64 + wv * 16;
  int rl = lane & 15;
  int kq = (lane >> 4) * 8;
  const unsigned short* ap = jb.A + (size_t)(rbw + rl) * KP + kq;
  f32x4 acc[13];
  #pragma unroll
  for (int t = 0; t < 13; ++t) acc[t] = (f32x4){0.f, 0.f, 0.f, 0.f};
  constexpr int NST = (KP + 63) / 64;
  #pragma unroll
  for (int s = 0; s < NST; ++s) {
    const int ks0 = s * 64;
    const int sw  = (KP - ks0 >= 64) ? 64 : (KP - ks0);
    const int cpr = sw / 8;
    __syncthreads();
    for (int idx = threadIdx.x; idx < 208 * cpr; idx += 256) {
      int row = idx / cpr, cw = idx - row * cpr;
      *(float4*)(shb + row * 72 + cw * 8) =
          *(const float4*)(jb.B + (size_t)row * KP + ks0 + cw * 8);
    }
    __syncthreads();
    for (int ksl = 0; ksl < sw; ksl += 32) {
      bf16x8 a0 = *(const bf16x8*)(ap + ks0 + ksl);
      const unsigned short* bl = shb + (size_t)rl * 72 + kq + ksl;
      #pragma unroll
      for (int t = 0; t < 13; ++t) {
        bf16x8 b = *(const bf16x8*)(bl + t * 16 * 72);
        acc[t] = __builtin_amdgcn_mfma_f32_16x16x32_bf16(a0, b, acc[t], 0, 0, 0);
      }
    }
  }
  int rg = (lane >> 4) * 4;
  if (jb.dot) {
    float p0[4] = {0.f, 0.f, 0.f, 0.f}, p1[4] = {0.f, 0.f, 0.f, 0.f};
    #pragma unroll
    for (int t = 0; t < 13; ++t) {
      int col = t * 16 + rl;
      float av = (col < 200) ? jb.a2[col] : 0.f;
      bool lo = (col < 100);
      #pragma unroll
      for (int g = 0; g < 4; ++g) {
        float v = acc[t][g] * av;
        if (lo) p0[g] += v; else p1[g] += v;
      }
    }
    #pragma unroll
    for (int off = 1; off < 16; off <<= 1) {
      #pragma unroll
      for (int g = 0; g < 4; ++g) {
        p0[g] += __shfl_xor(p0[g], off);
        p1[g] += __shfl_xor(p1[g], off);
      }
    }
    if (rl == 0) {
      #pragma unroll
      for (int g = 0; g < 4; ++g) {
        int row = rbw + rg + g;
        if (row < jb.M) {
          if (jb.dotmode == 1) { jb.dot[row * 2] = p0[g]; jb.dot[row * 2 + 1] = p1[g]; }
          else                 { jb.dot[row] = p0[g] + p1[g]; }
        }
      }
    }
  }
  if (jb.Cf || jb.Cbf) {
    __syncthreads();
    #pragma unroll
    for (int t = 0; t < 13; ++t) {
      #pragma unroll
      for (int g = 0; g < 4; ++g)
        clds[wv][rg + g][t * 16 + rl] = acc[t][g];
    }
    __syncthreads();
    #pragma unroll
    for (int i = 0; i < 13; ++i) {
      int idx = i * 64 + lane;
      if (idx < 800) {
        int r = idx / 50, cw = idx - r * 50;
        float4 v = *(const float4*)&clds[wv][r][cw * 4];
        int grow = rbw + r;
        if (grow < jb.M) {
          if (jb.Cf)
            *(float4*)(jb.Cf + (size_t)grow * 200 + cw * 4) = v;
          if (jb.Cbf) {
            ushort4 o = {bf16rne(v.x), bf16rne(v.y), bf16rne(v.z), bf16rne(v.w)};
            *(ushort4*)(jb.Cbf + (size_t)grow * jb.ldcb + cw * 4) = o;
          }
        }
      }
    }
  }
}

// ---------------- CSR scans ----------------
__global__ __launch_bounds__(256) void scanA(const int* __restrict__ deg, int* __restrict__ bsum, int n) {
  __shared__ int s[256];
  int t = threadIdx.x;
  int i = blockIdx.x * 256 + t;
  s[t] = (i < n) ? deg[i] : 0;
  __syncthreads();
  for (int off = 128; off > 0; off >>= 1) {
    if (t < off) s[t] += s[t + off];
    __syncthreads();
  }
  if (t == 0) bsum[blockIdx.x] = s[0];
}

// scanC with inline bsum prefix + LDS-aggregated light-degree histogram
__global__ __launch_bounds__(256) void scanC(const int* __restrict__ deg, const int* __restrict__ bsum,
                                             int* __restrict__ offs, int* __restrict__ pos,
                                             int* __restrict__ dhist, int n, int total) {
  __shared__ int sb[256];
  __shared__ int s[256];
  __shared__ int lh[65];
  int t = threadIdx.x;
  sb[t] = (t < 196) ? bsum[t] : 0;
  if (t < 65) lh[t] = 0;
  __syncthreads();
  for (int off = 1; off < 256; off <<= 1) {
    int add = (t >= off) ? sb[t - off] : 0;
    __syncthreads();
    sb[t] += add;
    __syncthreads();
  }
  int base = (blockIdx.x == 0) ? 0 : sb[blockIdx.x - 1];
  int i = blockIdx.x * 256 + t;
  int v = (i < n) ? deg[i] : 0;
  s[t] = v;
  __syncthreads();
  for (int off = 1; off < 256; off <<= 1) {
    int add = (t >= off) ? s[t - off] : 0;
    __syncthreads();
    s[t] += add;
    __syncthreads();
  }
  if (i < n) {
    int e = base + s[t] - v;
    offs[i] = e;
    pos[i]  = e;
    if (v <= 64) atomicAdd(&lh[v], 1);   // LDS atomic (on-CU, cheap)
  }
  if (i == 0) offs[n] = total;
  __syncthreads();
  if (t < 65 && lh[t]) atomicAdd(&dhist[t], lh[t]);  // <=65 global atomics/block
}

// fused: scatterk (y=0) + degree-bucketed buildLists (y=1)
__global__ __launch_bounds__(256) void scatBuild(const int* __restrict__ el, const int* __restrict__ et,
                                                 const int* __restrict__ tin, const int* __restrict__ offs,
                                                 int* __restrict__ pos, int2* __restrict__ edata,
                                                 int* __restrict__ lightL, int* __restrict__ heavyL,
                                                 int* __restrict__ cnts,
                                                 const int* __restrict__ dhist, int* __restrict__ dpos) {
  __shared__ int dpre[65];
  if (blockIdx.y == 0) {
    int i = blockIdx.x * 256 + threadIdx.x;
    if (i >= ETOT) return;
    int e0, e1, t1, t2f;
    if (i < NEDGE) {
      e0 = el[i]; e1 = el[NEDGE + i]; t1 = et[i]; t2f = 0;
    } else {
      const int* q = tin + (size_t)(i - NEDGE) * 4;
      e0 = q[3]; e1 = q[0]; t1 = q[1]; t2f = q[2] + 1;
    }
    int slot = atomicAdd(&pos[e0], 1);
    edata[slot] = make_int2(e1 | (t1 << 16), t2f | (e0 << 9));
    return;
  }
  if (threadIdx.x == 0) {
    int acc = 0;
    for (int d = 0; d <= 64; ++d) { dpre[d] = acc; acc += dhist[d]; }
  }
  __syncthreads();
  int i = blockIdx.x * 256 + threadIdx.x;
  int lane = threadIdx.x & 63;
  bool valid = (i < NN);
  int d = valid ? (offs[i + 1] - offs[i]) : -1;
  bool heavy = valid && (d > 64);
  bool light = valid && (d >= 0 && d <= 64);
  unsigned long long below = (1ULL << lane) - 1ULL;
  // heavy: wave-aggregated append
  unsigned long long mh = __ballot(heavy);
  int bh = 0;
  if (lane == 0 && mh) bh = atomicAdd(&cnts[1], __popcll(mh));
  bh = __shfl(bh, 0);
  if (heavy) heavyL[bh + __popcll(mh & below)] = i;
  // light count (for gather bounds)
  unsigned long long ml = __ballot(light);
  if (lane == 0 && ml) atomicAdd(&cnts[0], __popcll(ml));
  // light: degree-bucketed scatter, ballot-grouped per (wave, degree)
  unsigned long long remaining = ml;
  while (remaining) {
    int leader = __ffsll((unsigned long long)remaining) - 1;
    int dl = __shfl(d, leader);
    unsigned long long grp = __ballot(light && d == dl);
    int bse = 0;
    if (lane == leader) bse = atomicAdd(&dpos[dl], __popcll(grp));
    bse = __shfl(bse, leader);
    if (light && d == dl) lightL[dpre[dl] + bse + __popcll(grp & below)] = i;
    remaining &= ~grp;
  }
}

// ---------------- fused: edgeEE1 (y=0) + padx/maskset (y=1) ----------------
__global__ __launch_bounds__(256) void eeMisc1(const int2* __restrict__ edata,
                                               const float* __restrict__ ssrc,
                                               const float* __restrict__ sdst,
                                               const float* __restrict__ srel,
                                               float2* __restrict__ ee,
                                               unsigned short* __restrict__ xbf,
                                               const int* __restrict__ bi,
                                               float* __restrict__ maskA) {
  if (blockIdx.y == 1) {
    if (blockIdx.x < 42) {
      int i = blockIdx.x * 256 + threadIdx.x;
      if (i < (MP - NN) * 224) xbf[(size_t)NN * 224 + i] = 0;
    } else if (blockIdx.x < 42 + 256) {
      int t = (blockIdx.x - 42) * 256 + threadIdx.x;
      if (t < BATCH) maskA[bi[t * 3 + 2]] = 1.0f;
    }
    return;
  }
  int q = blockIdx.x * 256 + threadIdx.x;
  if (q >= ETOT) return;
  int2 ed = edata[q];
  int e1 = ed.x & 0xFFFF;
  int t1 = ((unsigned)ed.x) >> 16;
  int t2f = ed.y & 0x1FF;
  int e0 = ((unsigned)ed.y) >> 9;
  float p0 = ssrc[e0 * 2]     + sdst[e1 * 2]     + srel[t1 * 2];
  float p1 = ssrc[e0 * 2 + 1] + sdst[e1 * 2 + 1] + srel[t1 * 2 + 1];
  if (t2f) { int t2 = t2f - 1; p0 += srel[t2 * 2]; p1 += srel[t2 * 2 + 1]; }
  p0 = (p0 > 0.f) ? p0 : 0.2f * p0;
  p1 = (p1 > 0.f) ? p1 : 0.2f * p1;
  ee[q] = make_float2(__expf(-p0), __expf(-p1));
}

__global__ __launch_bounds__(256) void edgeEE2(const int2* __restrict__ edata,
                                               const float* __restrict__ ssrc,
                                               const float* __restrict__ sdst,
                                               const float* __restrict__ srel,
                                               float* __restrict__ ee) {
  int q = blockIdx.x * 256 + threadIdx.x;
  if (q >= ETOT) return;
  int2 ed = edata[q];
  int e1 = ed.x & 0xFFFF;
  int t1 = ((unsigned)ed.x) >> 16;
  int t2f = ed.y & 0x1FF;
  int e0 = ((unsigned)ed.y) >> 9;
  float p = ssrc[e0] + sdst[e1] + srel[t1];
  if (t2f) p += srel[t2f - 1];
  p = (p > 0.f) ? p : 0.2f * p;
  ee[q] = __expf(-p);
}

// ---------------- merged layer-1 gather ----------------
__global__ __launch_bounds__(512) void gather1M(const int* __restrict__ lightL, const int* __restrict__ heavyL,
    const int* __restrict__ cnts, const int* __restrict__ offs, const int2* __restrict__ edata,
    const float2* __restrict__ eeb,
    const unsigned short* __restrict__ srcb, const unsigned short* __restrict__ dstb,
    const unsigned short* __restrict__ relpb,
    unsigned short* __restrict__ xbf) {
  __shared__ float part[8][208];
  int w = threadIdx.x >> 6, lane = threadIdx.x & 63;
  bool act = lane < 50;
  int cb = lane * 4;
  float a0 = 0.f, a1 = 0.f, a2v = 0.f, a3 = 0.f, rs0 = 0.f, rs1 = 0.f;
  bool hd0 = (cb < 100);
  auto edgeop = [&](int2 ed, float2 ev) {
    int e1 = ed.x & 0xFFFF;
    int t1 = ((unsigned)ed.x) >> 16;
    int t2f = ed.y & 0x1FF;
    rs0 += ev.x; rs1 += ev.y;
    if (act) {
      ushort4 dv = *(const ushort4*)(dstb + (size_t)e1 * 200 + cb);
      ushort4 rv = *(const ushort4*)(relpb + (size_t)t1 * 200 + cb);
      float m0 = b2f(dv.x) + b2f(rv.x);
      float m1 = b2f(dv.y) + b2f(rv.y);
      float m2 = b2f(dv.z) + b2f(rv.z);
      float m3 = b2f(dv.w) + b2f(rv.w);
      if (t2f) {
        ushort4 r2 = *(const ushort4*)(relpb + (size_t)(t2f - 1) * 200 + cb);
        m0 += b2f(r2.x); m1 += b2f(r2.y); m2 += b2f(r2.z); m3 += b2f(r2.w);
      }
      float ee = hd0 ? ev.x : ev.y;
      a0 += ee * m0; a1 += ee * m1; a2v += ee * m2; a3 += ee * m3;
    }
  };
  if (blockIdx.x < HBMAX) {
    int hidx = blockIdx.x;
    if (hidx >= cnts[1]) return;
    int node = heavyL[hidx];
    int s = offs[node], e = offs[node + 1];
    int q = s + w;
    for (; q + 8 < e; q += 16) { edgeop(edata[q], eeb[q]); edgeop(edata[q + 8], eeb[q + 8]); }
    if (q < e) edgeop(edata[q], eeb[q]);
    if (act) { part[w][cb] = a0; part[w][cb + 1] = a1; part[w][cb + 2] = a2v; part[w][cb + 3] = a3; }
    if (lane == 0) { part[w][200] = rs0; part[w][201] = rs1; }
    __syncthreads();
    int t = threadIdx.x;
    if (t < 224) {
      unsigned short outv = 0;
      if (t < 200) {
        float a = 0.f, r0 = 0.f, r1 = 0.f;
        #pragma unroll
        for (int wv = 0; wv < 8; ++wv) { a += part[wv][t]; r0 += part[wv][200]; r1 += part[wv][201]; }
        float inv = (t < 100) ? 1.f / r0 : 1.f / r1;
        float v = b2f(srcb[(size_t)node * 200 + t]) + a * inv;
        v = (v > 0.f) ? v : expm1f(v);
        outv = bf16rne(v);
      }
      xbf[(size_t)node * 224 + t] = outv;
    }
    return;
  }
  int widx = (blockIdx.x - HBMAX) * 8 + w;
  if (widx >= cnts[0]) return;
  int node = lightL[widx];
  int s = offs[node], e = offs[node + 1];
  int q = s;
  for (; q + 1 < e; q += 2) { edgeop(edata[q], eeb[q]); edgeop(edata[q + 1], eeb[q + 1]); }
  if (q < e) edgeop(edata[q], eeb[q]);
  bool has = (e > s);
  unsigned short* xo = xbf + (size_t)node * 224;
  if (act) {
    float inv = has ? (hd0 ? 1.f / rs0 : 1.f / rs1) : 0.f;
    ushort4 sv = *(const ushort4*)(srcb + (size_t)node * 200 + cb);
    float v0 = has ? b2f(sv.x) + a0 * inv : 0.f;
    float v1 = has ? b2f(sv.y) + a1 * inv : 0.f;
    float v2 = has ? b2f(sv.z) + a2v * inv : 0.f;
    float v3 = has ? b2f(sv.w) + a3 * inv : 0.f;
    v0 = (v0 > 0.f) ? v0 : expm1f(v0);
    v1 = (v1 > 0.f) ? v1 : expm1f(v1);
    v2 = (v2 > 0.f) ? v2 : expm1f(v2);
    v3 = (v3 > 0.f) ? v3 : expm1f(v3);
    ushort4 ov = {bf16rne(v0), bf16rne(v1), bf16rne(v2), bf16rne(v3)};
    *(ushort4*)(xo + cb) = ov;
  } else if (lane < 56) {
    ushort4 z = {0, 0, 0, 0};
    *(ushort4*)(xo + cb) = z;
  }
}

// ---------------- merged layer-2 gather with FUSED final (elu + mask + l2norm -> out) ----------------
__global__ __launch_bounds__(512) void gather2M(const int* __restrict__ lightL, const int* __restrict__ heavyL,
    const int* __restrict__ cnts, const int* __restrict__ offs, const int2* __restrict__ edata,
    const float* __restrict__ eeb,
    const unsigned short* __restrict__ srcb, const unsigned short* __restrict__ dstb,
    const unsigned short* __restrict__ relpb,
    const unsigned short* __restrict__ xwb,
    const float* __restrict__ maskA, float* __restrict__ out) {
  __shared__ float part[8][208];
  __shared__ float red[512];
  int w = threadIdx.x >> 6, lane = threadIdx.x & 63;
  bool act = lane < 50;
  int cb = lane * 4;
  float a0 = 0.f, a1 = 0.f, a2v = 0.f, a3 = 0.f, rs = 0.f;
  auto edgeop = [&](int2 ed, float ee) {
    int e1 = ed.x & 0xFFFF;
    int t1 = ((unsigned)ed.x) >> 16;
    int t2f = ed.y & 0x1FF;
    rs += ee;
    if (act) {
      ushort4 dv = *(const ushort4*)(dstb + (size_t)e1 * 200 + cb);
      ushort4 rv = *(const ushort4*)(relpb + (size_t)t1 * 200 + cb);
      float m0 = b2f(dv.x) + b2f(rv.x);
      float m1 = b2f(dv.y) + b2f(rv.y);
      float m2 = b2f(dv.z) + b2f(rv.z);
      float m3 = b2f(dv.w) + b2f(rv.w);
      if (t2f) {
        ushort4 r2 = *(const ushort4*)(relpb + (size_t)(t2f - 1) * 200 + cb);
        m0 += b2f(r2.x); m1 += b2f(r2.y); m2 += b2f(r2.z); m3 += b2f(r2.w);
      }
      a0 += ee * m0; a1 += ee * m1; a2v += ee * m2; a3 += ee * m3;
    }
  };
  if (blockIdx.x < HBMAX) {
    int hidx = blockIdx.x;
    if (hidx >= cnts[1]) return;
    int node = heavyL[hidx];
    int s = offs[node], e = offs[node + 1];
    int q = s + w;
    for (; q + 8 < e; q += 16) { edgeop(edata[q], eeb[q]); edgeop(edata[q + 8], eeb[q + 8]); }
    if (q < e) edgeop(edata[q], eeb[q]);
    if (act) { part[w][cb] = a0; part[w][cb + 1] = a1; part[w][cb + 2] = a2v; part[w][cb + 3] = a3; }
    if (lane == 0) part[w][200] = rs;
    __syncthreads();
    int t = threadIdx.x;
    float m = maskA[node];
    float u = 0.f;
    if (t < 200) {
      float a = 0.f, r = 0.f;
      #pragma unroll
      for (int wv = 0; wv < 8; ++wv) { a += part[wv][t]; r += part[wv][200]; }
      float v = b2f(srcb[(size_t)node * 200 + t]) + a / r;
      v = (v > 0.f) ? v : expm1f(v);
      u = b2f(xwb[(size_t)node * 200 + t]) + m * v;
    }
    red[t] = u * u;
    __syncthreads();
    #pragma unroll
    for (int off = 256; off > 0; off >>= 1) {
      if (t < off) red[t] += red[t + off];
      __syncthreads();
    }
    float inv = 1.f / fmaxf(sqrtf(red[0]), 1e-12f);
    if (t < 200) out[(size_t)node * 200 + t] = u * inv;
    return;
  }
  int widx = (blockIdx.x - HBMAX) * 8 + w;
  if (widx >= cnts[0]) return;
  int node = lightL[widx];
  int s = offs[node], e = offs[node + 1];
  int q = s;
  for (; q + 1 < e; q += 2) { edgeop(edata[q], eeb[q]); edgeop(edata[q + 1], eeb[q + 1]); }
  if (q < e) edgeop(edata[q], eeb[q]);
  bool has = (e > s);
  float m = maskA[node];
  float u0 = 0.f, u1 = 0.f, u2 = 0.f, u3 = 0.f;
  if (act) {
    float inv = has ? 1.f / rs : 0.f;
    ushort4 sv = *(const ushort4*)(srcb + (size_t)node * 200 + cb);
    float v0 = has ? b2f(sv.x) + a0 * inv : 0.f;
    float v1 = has ? b2f(sv.y) + a1 * inv : 0.f;
    float v2 = has ? b2f(sv.z) + a2v * inv : 0.f;
    float v3 = has ? b2f(sv.w) + a3 * inv : 0.f;
    v0 = (v0 > 0.f) ? v0 : expm1f(v0);
    v1 = (v1 > 0.f) ? v1 : expm1f(v1);
    v2 = (v2 > 0.f) ? v2 : expm1f(v2);
    v3 = (v3 > 0.f) ? v3 : expm1f(v3);
    ushort4 xv = *(const ushort4*)(xwb + (size_t)node * 200 + cb);
    u0 = b2f(xv.x) + m * v0;
    u1 = b2f(xv.y) + m * v1;
    u2 = b2f(xv.z) + m * v2;
    u3 = b2f(xv.w) + m * v3;
  }
  float ss = u0 * u0 + u1 * u1 + u2 * u2 + u3 * u3;
  #pragma unroll
  for (int off = 1; off < 64; off <<= 1) ss += __shfl_xor(ss, off);
  float inv = 1.f / fmaxf(sqrtf(ss), 1e-12f);
  if (act) {
    float4 ov = {u0 * inv, u1 * inv, u2 * inv, u3 * inv};
    *(float4*)(out + (size_t)node * 200 + cb) = ov;
  }
}

extern "C" void kernel_launch(void* const* d_in, const int* in_sizes, int n_in,
                              void* d_out, int out_size, void* d_ws, size_t ws_size,
                              hipStream_t stream) {
  (void)in_sizes; (void)n_in; (void)out_size; (void)ws_size;
  const float* ent      = (const float*)d_in[0];
  const float* rel      = (const float*)d_in[1];
  const float* a_heads  = (const float*)d_in[3];
  const float* a2_heads = (const float*)d_in[4];
  const float* W_gat    = (const float*)d_in[5];
  const float* a_out    = (const float*)d_in[6];
  const float* a2_out   = (const float*)d_in[7];
  const float* W_ent    = (const float*)d_in[8];
  const int* edge_list  = (const int*)d_in[9];
  const int* edge_type  = (const int*)d_in[10];
  const int* tin        = (const int*)d_in[11];
  const int* binp       = (const int*)d_in[12];

  float* out    = (float*)d_out;
  float* outrel = out + 10000000;     // (500,200) output 1

  float* ws = (float*)d_ws;
  unsigned short* bufSb  = (unsigned short*)ws;                // NN*200 bf16
  unsigned short* dstD   = (unsigned short*)(ws + 5000000);
  unsigned short* relp1b = (unsigned short*)(ws + 10000000);
  unsigned short* relp2b = (unsigned short*)(ws + 10050000);
  float* ssrc1 = ws + 10100000;
  float* sdst1 = ws + 10200000;
  float* s2src = ws + 10300000;
  float* s2dst = ws + 10350000;
  float* srel1 = ws + 10400000;
  float* s2rel = ws + 10402000;
  // ---- contiguous zero region ----
  float* maskA = ws + 10404000;                                 // 50k f32
  int*   deg   = (int*)(ws + 10454000);                         // 50k int
  int*   cnts  = (int*)(ws + 10504000);                         // 8 int
  int*   dhist = (int*)(ws + 10504008);                         // 65 int
  int*   dpos  = (int*)(ws + 10504080);                         // 65 int
  unsigned short* orelb = (unsigned short*)(ws + 10504152);     // 512*224 ushort
  // zero region ends at ws + 10561496
  unsigned short* x0nbf = (unsigned short*)(ws + 10570000);     // MP*128
  unsigned short* xbf   = (unsigned short*)(ws + 13780000);     // MP*224
  unsigned short* B1s   = (unsigned short*)(ws + 19390000);
  unsigned short* B1d   = (unsigned short*)(ws + 19405000);
  unsigned short* Brel1 = (unsigned short*)(ws + 19420000);
  unsigned short* Bxw   = (unsigned short*)(ws + 19435000);
  unsigned short* Bwgat = (unsigned short*)(ws + 19450000);
  unsigned short* B2s   = (unsigned short*)(ws + 19465000);
  unsigned short* B2d   = (unsigned short*)(ws + 19490000);
  unsigned short* B2rel = (unsigned short*)(ws + 19515000);
  unsigned short* relbf = (unsigned short*)(ws + 19540000);     // 512*128
  float2* eeb1 = (float2*)(ws + 19580000);                      // ETOT float2
  float*  eeb2 = ws + 20330000;                                 // ETOT float
  unsigned short* xwb = (unsigned short*)(ws + 20710000);       // NN*200 bf16
  int* ibase  = (int*)(ws + 25710000);
  int* offs   = ibase;                 // 50k+1
  int* pos    = ibase + 50016;
  int* bsum   = ibase + 100016;        // 256
  int* lightL = ibase + 100288;
  int* heavyL = ibase + 150288;
  int2* edata = (int2*)(ibase + 200288);

  hipMemsetAsync(maskA, 0, (size_t)(10561496 - 10404000) * 4, stream);

  // l2norm + histk + weight conversions
  {
    dim3 g(12512, 3);
    startk<<<g, 256, 0, stream>>>(ent, x0nbf, edge_list, tin, deg,
                                  rel, a_heads, W_ent, W_gat, a_out,
                                  B1s, B1d, Brel1, Bxw, Bwgat, B2s, B2d, B2rel, relbf);
  }
  scanA<<<196, 256, 0, stream>>>(deg, bsum, NN);
  scanC<<<196, 256, 0, stream>>>(deg, bsum, offs, pos, dhist, NN, ETOT);
  {
    dim3 g(1465, 2);
    scatBuild<<<g, 256, 0, stream>>>(edge_list, edge_type, tin, offs, pos, edata,
                                     lightL, heavyL, cnts, dhist, dpos);
  }

  // layer-1 projections + xw(bf16) + rel projections + out_relation_1, one 5-job launch
  {
    GJob js    = {x0nbf, NN,    B1s,   nullptr, bufSb,  200, a2_heads, ssrc1, 1};
    GJob jd    = {x0nbf, NN,    B1d,   nullptr, dstD,   200, a2_heads, sdst1, 1};
    GJob jx    = {x0nbf, NN,    Bxw,   nullptr, xwb,    200, nullptr,  nullptr, 0};
    GJob jrel1 = {relbf, NRELS, Brel1, nullptr, relp1b, 200, a2_heads, srel1, 1};
    GJob jorel = {relbf, NRELS, Bwgat, outrel,  orelb,  224, nullptr,  nullptr, 0};
    dim3 g(782, 5);
    gemm_multi<128><<<g, 256, 0, stream>>>(js, jd, jx, jrel1, jorel);
  }

  // edgeEE1 + padx + maskset
  {
    dim3 g(1465, 2);
    eeMisc1<<<g, 256, 0, stream>>>(edata, ssrc1, sdst1, srel1, eeb1, xbf, binp, maskA);
  }

  gather1M<<<HBMAX + LB1, 512, 0, stream>>>(lightL, heavyL, cnts, offs, edata, eeb1,
                                            bufSb, dstD, relp1b, xbf);

  // layer-2 projections + relp2, one 3-job launch
  {
    GJob js    = {xbf,   NN,    B2s,   nullptr, bufSb,  200, a2_out, s2src, 2};
    GJob jd    = {xbf,   NN,    B2d,   nullptr, dstD,   200, a2_out, s2dst, 2};
    GJob jrp2  = {orelb, NRELS, B2rel, nullptr, relp2b, 200, a2_out, s2rel, 2};
    GJob jz    = {nullptr, 0, nullptr, nullptr, nullptr, 0, nullptr, nullptr, 0};
    dim3 g(782, 3);
    gemm_multi<224><<<g, 256, 0, stream>>>(js, jd, jrp2, jz, jz);
  }

  edgeEE2<<<(ETOT + 255) / 256, 256, 0, stream>>>(edata, s2src, s2dst, s2rel, eeb2);

  // gather2 with fused elu+mask+l2norm epilogue -> out
  gather2M<<<HBMAX + LB1, 512, 0, stream>>>(lightL, heavyL, cnts, offs, edata, eeb2,
                                            bufSb, dstD, relp2b, xwb, maskA, out);
}

// Round 17
// 369.944 us; speedup vs baseline: 1.6680x; 1.1550x over previous
//
#include <hip/hip_runtime.h>
#include <math.h>

#define NN    50000
#define MP    50048    // padded rows (782*64)
#define NEDGE 250000
#define NHOPE 125000
#define ETOT  375000
#define NRELS 500
#define BATCH 65536
#define LB1   6250     // light blocks (8 waves each -> 50000 waves)
#define HBMAX 5769     // max heavy nodes (deg>64): 375000/65

typedef __attribute__((ext_vector_type(8))) short bf16x8;
typedef __attribute__((ext_vector_type(4))) float f32x4;

__device__ __forceinline__ unsigned short bf16rne(float f) {
  unsigned u = __float_as_uint(f);
  unsigned r = (u + 0x7FFFu + ((u >> 16) & 1u)) >> 16;
  return (unsigned short)r;
}
__device__ __forceinline__ float b2f(unsigned short u) {
  return __uint_as_float(((unsigned)u) << 16);
}

struct GJob {
  const unsigned short* A;   // padded rows x KP bf16
  int M;                     // valid rows
  const unsigned short* B;   // 208 x KP bf16
  float* Cf;                 // f32 out (ld 200) or null
  unsigned short* Cbf;       // bf16 out (ld ldcb) or null
  int ldcb;
  const float* a2;           // 200 floats or null
  float* dot;                // per-row scalar(s) or null
  int dotmode;               // 1 = split at 100, 2 = single sum
};

// ---------------- fused: l2norm (y=0) + histk (y=1) + weight conversions (y=2) ----------------
__global__ __launch_bounds__(256) void startk(const float* __restrict__ in,
                                              unsigned short* __restrict__ out,
                                              const int* __restrict__ el, const int* __restrict__ tin,
                                              int* __restrict__ deg,
                                              const float* __restrict__ rel,
                                              const float* __restrict__ ah,
                                              const float* __restrict__ W_ent,
                                              const float* __restrict__ W_gat,
                                              const float* __restrict__ a_out,
                                              unsigned short* __restrict__ B1s,
                                              unsigned short* __restrict__ B1d,
                                              unsigned short* __restrict__ Brel1,
                                              unsigned short* __restrict__ Bxw,
                                              unsigned short* __restrict__ Bwgat,
                                              unsigned short* __restrict__ B2s,
                                              unsigned short* __restrict__ B2d,
                                              unsigned short* __restrict__ B2rel,
                                              unsigned short* __restrict__ relbf) {
  if (blockIdx.y == 1) {
    int i = blockIdx.x * 256 + threadIdx.x;
    if (i < ETOT) {
      int e0 = (i < NEDGE) ? el[i] : tin[(size_t)(i - NEDGE) * 4 + 3];
      atomicAdd(&deg[e0], 1);
    }
    return;
  }
  if (blockIdx.y == 2) {
    const int S1 = 26624, S2 = 46592;   // 208*128, 208*224
    int idx = blockIdx.x * 256 + threadIdx.x;
    if (idx < 3 * S1) {                 // B1s / B1d / Brel1
      int y = idx / S1, r = idx - y * S1;
      int j = r >> 7, k = r & 127;
      float v = 0.f;
      if (j < 200 && k < 100)
        v = ah[((j < 100) ? 0 : 30000) + (j % 100) * 300 + y * 100 + k];
      (y == 0 ? B1s : (y == 1 ? B1d : Brel1))[r] = bf16rne(v);
    } else if (idx < 4 * S1) {          // Bxw : W_ent^T
      int r = idx - 3 * S1;
      int j = r >> 7, k = r & 127;
      float v = (j < 200 && k < 100) ? W_ent[(size_t)k * 200 + j] : 0.f;
      Bxw[r] = bf16rne(v);
    } else if (idx < 5 * S1) {          // Bwgat : W_gat^T
      int r = idx - 4 * S1;
      int j = r >> 7, k = r & 127;
      float v = (j < 200 && k < 100) ? W_gat[(size_t)k * 200 + j] : 0.f;
      Bwgat[r] = bf16rne(v);
    } else if (idx < 5 * S1 + 3 * S2) { // B2s / B2d / B2rel
      int r = idx - 5 * S1;
      int y = r / S2; r -= y * S2;
      int j = r / 224, k = r - j * 224;
      float v = (j < 200 && k < 200) ? a_out[(size_t)j * 600 + y * 200 + k] : 0.f;
      (y == 0 ? B2s : (y == 1 ? B2d : B2rel))[r] = bf16rne(v);
    } else if (idx < 5 * S1 + 3 * S2 + 65536) {  // relbf 512x128
      int r = idx - 5 * S1 - 3 * S2;
      int j = r >> 7, k = r & 127;
      float v = (j < 500 && k < 100) ? rel[(size_t)j * 100 + k] : 0.f;
      relbf[r] = bf16rne(v);
    }
    return;
  }
  int row  = blockIdx.x * 4 + (threadIdx.x >> 6);
  int lane = threadIdx.x & 63;
  if (row >= MP) return;
  unsigned short* o = out + (size_t)row * 128;
  if (row >= NN) { o[lane] = 0; o[lane + 64] = 0; return; }
  const float* r = in + (size_t)row * 100;
  float v0 = r[lane];
  float v1 = (lane + 64 < 100) ? r[lane + 64] : 0.f;
  float ss = v0 * v0 + v1 * v1;
  #pragma unroll
  for (int off = 1; off < 64; off <<= 1) ss += __shfl_xor(ss, off);
  float inv = 1.f / fmaxf(sqrtf(ss), 1e-12f);
  o[lane] = bf16rne(v0 * inv);
  o[lane + 64] = (lane + 64 < 100) ? bf16rne(v1 * inv) : (unsigned short)0;
}

// ---------------- multi-job bf16 MFMA GEMM, LDS-staged B, LDS-coalesced epilogue ----------------
template<int KP>
__global__ __launch_bounds__(256) void gemm_multi(GJob j0, GJob j1, GJob j2, GJob j3, GJob j4) {
  __shared__ __attribute__((aligned(16))) char smem[54272];
  unsigned short* shb = (unsigned short*)smem;
  float (*clds)[16][212] = (float (*)[16][212])smem;   // [4][16][212]
  GJob jb = (blockIdx.y == 0) ? j0 : (blockIdx.y == 1) ? j1 : (blockIdx.y == 2) ? j2
          : (blockIdx.y == 3) ? j3 : j4;
  if (blockIdx.x * 64 >= jb.M) return;
  int wv = threadIdx.x >> 6, lane = threadIdx.x & 63;
  int rbw = blockIdx.x * 64 + wv * 16;
  int rl = lane & 15;
  int kq = (lane >> 4) * 8;
  const unsigned short* ap = jb.A + (size_t)(rbw + rl) * KP + kq;
  f32x4 acc[13];
  #pragma unroll
  for (int t = 0; t < 13; ++t) acc[t] = (f32x4){0.f, 0.f, 0.f, 0.f};
  constexpr int NST = (KP + 63) / 64;
  #pragma unroll
  for (int s = 0; s < NST; ++s) {
    const int ks0 = s * 64;
    const int sw  = (KP - ks0 >= 64) ? 64 : (KP - ks0);
    const int cpr = sw / 8;
    __syncthreads();
    for (int idx = threadIdx.x; idx < 208 * cpr; idx += 256) {
      int row = idx / cpr, cw = idx - row * cpr;
      *(float4*)(shb + row * 72 + cw * 8) =
          *(const float4*)(jb.B + (size_t)row * KP + ks0 + cw * 8);
    }
    __syncthreads();
    for (int ksl = 0; ksl < sw; ksl += 32) {
      bf16x8 a0 = *(const bf16x8*)(ap + ks0 + ksl);
      const unsigned short* bl = shb + (size_t)rl * 72 + kq + ksl;
      #pragma unroll
      for (int t = 0; t < 13; ++t) {
        bf16x8 b = *(const bf16x8*)(bl + t * 16 * 72);
        acc[t] = __builtin_amdgcn_mfma_f32_16x16x32_bf16(a0, b, acc[t], 0, 0, 0);
      }
    }
  }
  int rg = (lane >> 4) * 4;
  if (jb.dot) {
    float p0[4] = {0.f, 0.f, 0.f, 0.f}, p1[4] = {0.f, 0.f, 0.f, 0.f};
    #pragma unroll
    for (int t = 0; t < 13; ++t) {
      int col = t * 16 + rl;
      float av = (col < 200) ? jb.a2[col] : 0.f;
      bool lo = (col < 100);
      #pragma unroll
      for (int g = 0; g < 4; ++g) {
        float v = acc[t][g] * av;
        if (lo) p0[g] += v; else p1[g] += v;
      }
    }
    #pragma unroll
    for (int off = 1; off < 16; off <<= 1) {
      #pragma unroll
      for (int g = 0; g < 4; ++g) {
        p0[g] += __shfl_xor(p0[g], off);
        p1[g] += __shfl_xor(p1[g], off);
      }
    }
    if (rl == 0) {
      #pragma unroll
      for (int g = 0; g < 4; ++g) {
        int row = rbw + rg + g;
        if (row < jb.M) {
          if (jb.dotmode == 1) { jb.dot[row * 2] = p0[g]; jb.dot[row * 2 + 1] = p1[g]; }
          else                 { jb.dot[row] = p0[g] + p1[g]; }
        }
      }
    }
  }
  if (jb.Cf || jb.Cbf) {
    __syncthreads();
    #pragma unroll
    for (int t = 0; t < 13; ++t) {
      #pragma unroll
      for (int g = 0; g < 4; ++g)
        clds[wv][rg + g][t * 16 + rl] = acc[t][g];
    }
    __syncthreads();
    #pragma unroll
    for (int i = 0; i < 13; ++i) {
      int idx = i * 64 + lane;
      if (idx < 800) {
        int r = idx / 50, cw = idx - r * 50;
        float4 v = *(const float4*)&clds[wv][r][cw * 4];
        int grow = rbw + r;
        if (grow < jb.M) {
          if (jb.Cf)
            *(float4*)(jb.Cf + (size_t)grow * 200 + cw * 4) = v;
          if (jb.Cbf) {
            ushort4 o = {bf16rne(v.x), bf16rne(v.y), bf16rne(v.z), bf16rne(v.w)};
            *(ushort4*)(jb.Cbf + (size_t)grow * jb.ldcb + cw * 4) = o;
          }
        }
      }
    }
  }
}

// ---------------- CSR scans ----------------
__global__ __launch_bounds__(256) void scanA(const int* __restrict__ deg, int* __restrict__ bsum, int n) {
  __shared__ int s[256];
  int t = threadIdx.x;
  int i = blockIdx.x * 256 + t;
  s[t] = (i < n) ? deg[i] : 0;
  __syncthreads();
  for (int off = 128; off > 0; off >>= 1) {
    if (t < off) s[t] += s[t + off];
    __syncthreads();
  }
  if (t == 0) bsum[blockIdx.x] = s[0];
}

// scanC with inline bsum prefix (no scanB)
__global__ __launch_bounds__(256) void scanC(const int* __restrict__ deg, const int* __restrict__ bsum,
                                             int* __restrict__ offs, int* __restrict__ pos, int n, int total) {
  __shared__ int sb[256];
  __shared__ int s[256];
  int t = threadIdx.x;
  sb[t] = (t < 196) ? bsum[t] : 0;
  __syncthreads();
  for (int off = 1; off < 256; off <<= 1) {
    int add = (t >= off) ? sb[t - off] : 0;
    __syncthreads();
    sb[t] += add;
    __syncthreads();
  }
  int base = (blockIdx.x == 0) ? 0 : sb[blockIdx.x - 1];
  int i = blockIdx.x * 256 + t;
  int v = (i < n) ? deg[i] : 0;
  s[t] = v;
  __syncthreads();
  for (int off = 1; off < 256; off <<= 1) {
    int add = (t >= off) ? s[t - off] : 0;
    __syncthreads();
    s[t] += add;
    __syncthreads();
  }
  if (i < n) {
    int e = base + s[t] - v;
    offs[i] = e;
    pos[i]  = e;
  }
  if (i == 0) offs[n] = total;
}

// fused: scatterk (y=0) + buildLists (y=1). edata: .x = e1|(t1<<16), .y = t2f|(e0<<9)
__global__ __launch_bounds__(256) void scatBuild(const int* __restrict__ el, const int* __restrict__ et,
                                                 const int* __restrict__ tin, const int* __restrict__ offs,
                                                 int* __restrict__ pos, int2* __restrict__ edata,
                                                 int* __restrict__ lightL, int* __restrict__ heavyL,
                                                 int* __restrict__ cnts) {
  if (blockIdx.y == 0) {
    int i = blockIdx.x * 256 + threadIdx.x;
    if (i >= ETOT) return;
    int e0, e1, t1, t2f;
    if (i < NEDGE) {
      e0 = el[i]; e1 = el[NEDGE + i]; t1 = et[i]; t2f = 0;
    } else {
      const int* q = tin + (size_t)(i - NEDGE) * 4;
      e0 = q[3]; e1 = q[0]; t1 = q[1]; t2f = q[2] + 1;
    }
    int slot = atomicAdd(&pos[e0], 1);
    edata[slot] = make_int2(e1 | (t1 << 16), t2f | (e0 << 9));
    return;
  }
  int i = blockIdx.x * 256 + threadIdx.x;
  int lane = threadIdx.x & 63;
  bool valid = (i < NN);
  int d = valid ? (offs[i + 1] - offs[i]) : 0;
  bool heavy = valid && (d > 64);
  bool light = valid && (d <= 64);
  unsigned long long mh = __ballot(heavy);
  unsigned long long ml = __ballot(light);
  unsigned long long below = (1ULL << lane) - 1ULL;
  int bh = 0, bl = 0;
  if (lane == 0) {
    if (mh) bh = atomicAdd(&cnts[1], __popcll(mh));
    if (ml) bl = atomicAdd(&cnts[0], __popcll(ml));
  }
  bh = __shfl(bh, 0);
  bl = __shfl(bl, 0);
  if (heavy) heavyL[bh + __popcll(mh & below)] = i;
  if (light) lightL[bl + __popcll(ml & below)] = i;
}

// ---------------- fused: edgeEE1 (y=0) + padx/maskset (y=1) ----------------
__global__ __launch_bounds__(256) void eeMisc1(const int2* __restrict__ edata,
                                               const float* __restrict__ ssrc,
                                               const float* __restrict__ sdst,
                                               const float* __restrict__ srel,
                                               float2* __restrict__ ee,
                                               unsigned short* __restrict__ xbf,
                                               const int* __restrict__ bi,
                                               float* __restrict__ maskA) {
  if (blockIdx.y == 1) {
    if (blockIdx.x < 42) {
      int i = blockIdx.x * 256 + threadIdx.x;
      if (i < (MP - NN) * 224) xbf[(size_t)NN * 224 + i] = 0;
    } else if (blockIdx.x < 42 + 256) {
      int t = (blockIdx.x - 42) * 256 + threadIdx.x;
      if (t < BATCH) maskA[bi[t * 3 + 2]] = 1.0f;
    }
    return;
  }
  int q = blockIdx.x * 256 + threadIdx.x;
  if (q >= ETOT) return;
  int2 ed = edata[q];
  int e1 = ed.x & 0xFFFF;
  int t1 = ((unsigned)ed.x) >> 16;
  int t2f = ed.y & 0x1FF;
  int e0 = ((unsigned)ed.y) >> 9;
  float p0 = ssrc[e0 * 2]     + sdst[e1 * 2]     + srel[t1 * 2];
  float p1 = ssrc[e0 * 2 + 1] + sdst[e1 * 2 + 1] + srel[t1 * 2 + 1];
  if (t2f) { int t2 = t2f - 1; p0 += srel[t2 * 2]; p1 += srel[t2 * 2 + 1]; }
  p0 = (p0 > 0.f) ? p0 : 0.2f * p0;
  p1 = (p1 > 0.f) ? p1 : 0.2f * p1;
  ee[q] = make_float2(__expf(-p0), __expf(-p1));
}

__global__ __launch_bounds__(256) void edgeEE2(const int2* __restrict__ edata,
                                               const float* __restrict__ ssrc,
                                               const float* __restrict__ sdst,
                                               const float* __restrict__ srel,
                                               float* __restrict__ ee) {
  int q = blockIdx.x * 256 + threadIdx.x;
  if (q >= ETOT) return;
  int2 ed = edata[q];
  int e1 = ed.x & 0xFFFF;
  int t1 = ((unsigned)ed.x) >> 16;
  int t2f = ed.y & 0x1FF;
  int e0 = ((unsigned)ed.y) >> 9;
  float p = ssrc[e0] + sdst[e1] + srel[t1];
  if (t2f) p += srel[t2f - 1];
  p = (p > 0.f) ? p : 0.2f * p;
  ee[q] = __expf(-p);
}

// ---------------- merged layer-1 gather ----------------
__global__ __launch_bounds__(512) void gather1M(const int* __restrict__ lightL, const int* __restrict__ heavyL,
    const int* __restrict__ cnts, const int* __restrict__ offs, const int2* __restrict__ edata,
    const float2* __restrict__ eeb,
    const unsigned short* __restrict__ srcb, const unsigned short* __restrict__ dstb,
    const unsigned short* __restrict__ relpb,
    unsigned short* __restrict__ xbf) {
  __shared__ float part[8][208];
  int w = threadIdx.x >> 6, lane = threadIdx.x & 63;
  bool act = lane < 50;
  int cb = lane * 4;
  float a0 = 0.f, a1 = 0.f, a2v = 0.f, a3 = 0.f, rs0 = 0.f, rs1 = 0.f;
  bool hd0 = (cb < 100);
  auto edgeop = [&](int2 ed, float2 ev) {
    int e1 = ed.x & 0xFFFF;
    int t1 = ((unsigned)ed.x) >> 16;
    int t2f = ed.y & 0x1FF;
    rs0 += ev.x; rs1 += ev.y;
    if (act) {
      ushort4 dv = *(const ushort4*)(dstb + (size_t)e1 * 200 + cb);
      ushort4 rv = *(const ushort4*)(relpb + (size_t)t1 * 200 + cb);
      float m0 = b2f(dv.x) + b2f(rv.x);
      float m1 = b2f(dv.y) + b2f(rv.y);
      float m2 = b2f(dv.z) + b2f(rv.z);
      float m3 = b2f(dv.w) + b2f(rv.w);
      if (t2f) {
        ushort4 r2 = *(const ushort4*)(relpb + (size_t)(t2f - 1) * 200 + cb);
        m0 += b2f(r2.x); m1 += b2f(r2.y); m2 += b2f(r2.z); m3 += b2f(r2.w);
      }
      float ee = hd0 ? ev.x : ev.y;
      a0 += ee * m0; a1 += ee * m1; a2v += ee * m2; a3 += ee * m3;
    }
  };
  if (blockIdx.x < HBMAX) {
    int hidx = blockIdx.x;
    if (hidx >= cnts[1]) return;
    int node = heavyL[hidx];
    int s = offs[node], e = offs[node + 1];
    int q = s + w;
    for (; q + 8 < e; q += 16) { edgeop(edata[q], eeb[q]); edgeop(edata[q + 8], eeb[q + 8]); }
    if (q < e) edgeop(edata[q], eeb[q]);
    if (act) { part[w][cb] = a0; part[w][cb + 1] = a1; part[w][cb + 2] = a2v; part[w][cb + 3] = a3; }
    if (lane == 0) { part[w][200] = rs0; part[w][201] = rs1; }
    __syncthreads();
    int t = threadIdx.x;
    if (t < 224) {
      unsigned short outv = 0;
      if (t < 200) {
        float a = 0.f, r0 = 0.f, r1 = 0.f;
        #pragma unroll
        for (int wv = 0; wv < 8; ++wv) { a += part[wv][t]; r0 += part[wv][200]; r1 += part[wv][201]; }
        float inv = (t < 100) ? 1.f / r0 : 1.f / r1;
        float v = b2f(srcb[(size_t)node * 200 + t]) + a * inv;
        v = (v > 0.f) ? v : expm1f(v);
        outv = bf16rne(v);
      }
      xbf[(size_t)node * 224 + t] = outv;
    }
    return;
  }
  int widx = (blockIdx.x - HBMAX) * 8 + w;
  if (widx >= cnts[0]) return;
  int node = lightL[widx];
  int s = offs[node], e = offs[node + 1];
  int q = s;
  for (; q + 1 < e; q += 2) { edgeop(edata[q], eeb[q]); edgeop(edata[q + 1], eeb[q + 1]); }
  if (q < e) edgeop(edata[q], eeb[q]);
  bool has = (e > s);
  unsigned short* xo = xbf + (size_t)node * 224;
  if (act) {
    float inv = has ? (hd0 ? 1.f / rs0 : 1.f / rs1) : 0.f;
    ushort4 sv = *(const ushort4*)(srcb + (size_t)node * 200 + cb);
    float v0 = has ? b2f(sv.x) + a0 * inv : 0.f;
    float v1 = has ? b2f(sv.y) + a1 * inv : 0.f;
    float v2 = has ? b2f(sv.z) + a2v * inv : 0.f;
    float v3 = has ? b2f(sv.w) + a3 * inv : 0.f;
    v0 = (v0 > 0.f) ? v0 : expm1f(v0);
    v1 = (v1 > 0.f) ? v1 : expm1f(v1);
    v2 = (v2 > 0.f) ? v2 : expm1f(v2);
    v3 = (v3 > 0.f) ? v3 : expm1f(v3);
    ushort4 ov = {bf16rne(v0), bf16rne(v1), bf16rne(v2), bf16rne(v3)};
    *(ushort4*)(xo + cb) = ov;
  } else if (lane < 56) {
    ushort4 z = {0, 0, 0, 0};
    *(ushort4*)(xo + cb) = z;
  }
}

// ---------------- merged layer-2 gather with FUSED final (elu + mask + l2norm -> out) ----------------
__global__ __launch_bounds__(512) void gather2M(const int* __restrict__ lightL, const int* __restrict__ heavyL,
    const int* __restrict__ cnts, const int* __restrict__ offs, const int2* __restrict__ edata,
    const float* __restrict__ eeb,
    const unsigned short* __restrict__ srcb, const unsigned short* __restrict__ dstb,
    const unsigned short* __restrict__ relpb,
    const unsigned short* __restrict__ xwb,
    const float* __restrict__ maskA, float* __restrict__ out) {
  __shared__ float part[8][208];
  __shared__ float red[512];
  int w = threadIdx.x >> 6, lane = threadIdx.x & 63;
  bool act = lane < 50;
  int cb = lane * 4;
  float a0 = 0.f, a1 = 0.f, a2v = 0.f, a3 = 0.f, rs = 0.f;
  auto edgeop = [&](int2 ed, float ee) {
    int e1 = ed.x & 0xFFFF;
    int t1 = ((unsigned)ed.x) >> 16;
    int t2f = ed.y & 0x1FF;
    rs += ee;
    if (act) {
      ushort4 dv = *(const ushort4*)(dstb + (size_t)e1 * 200 + cb);
      ushort4 rv = *(const ushort4*)(relpb + (size_t)t1 * 200 + cb);
      float m0 = b2f(dv.x) + b2f(rv.x);
      float m1 = b2f(dv.y) + b2f(rv.y);
      float m2 = b2f(dv.z) + b2f(rv.z);
      float m3 = b2f(dv.w) + b2f(rv.w);
      if (t2f) {
        ushort4 r2 = *(const ushort4*)(relpb + (size_t)(t2f - 1) * 200 + cb);
        m0 += b2f(r2.x); m1 += b2f(r2.y); m2 += b2f(r2.z); m3 += b2f(r2.w);
      }
      a0 += ee * m0; a1 += ee * m1; a2v += ee * m2; a3 += ee * m3;
    }
  };
  if (blockIdx.x < HBMAX) {
    int hidx = blockIdx.x;
    if (hidx >= cnts[1]) return;
    int node = heavyL[hidx];
    int s = offs[node], e = offs[node + 1];
    int q = s + w;
    for (; q + 8 < e; q += 16) { edgeop(edata[q], eeb[q]); edgeop(edata[q + 8], eeb[q + 8]); }
    if (q < e) edgeop(edata[q], eeb[q]);
    if (act) { part[w][cb] = a0; part[w][cb + 1] = a1; part[w][cb + 2] = a2v; part[w][cb + 3] = a3; }
    if (lane == 0) part[w][200] = rs;
    __syncthreads();
    int t = threadIdx.x;
    float m = maskA[node];
    float u = 0.f;
    if (t < 200) {
      float a = 0.f, r = 0.f;
      #pragma unroll
      for (int wv = 0; wv < 8; ++wv) { a += part[wv][t]; r += part[wv][200]; }
      float v = b2f(srcb[(size_t)node * 200 + t]) + a / r;
      v = (v > 0.f) ? v : expm1f(v);
      u = b2f(xwb[(size_t)node * 200 + t]) + m * v;
    }
    red[t] = u * u;
    __syncthreads();
    #pragma unroll
    for (int off = 256; off > 0; off >>= 1) {
      if (t < off) red[t] += red[t + off];
      __syncthreads();
    }
    float inv = 1.f / fmaxf(sqrtf(red[0]), 1e-12f);
    if (t < 200) out[(size_t)node * 200 + t] = u * inv;
    return;
  }
  int widx = (blockIdx.x - HBMAX) * 8 + w;
  if (widx >= cnts[0]) return;
  int node = lightL[widx];
  int s = offs[node], e = offs[node + 1];
  int q = s;
  for (; q + 1 < e; q += 2) { edgeop(edata[q], eeb[q]); edgeop(edata[q + 1], eeb[q + 1]); }
  if (q < e) edgeop(edata[q], eeb[q]);
  bool has = (e > s);
  float m = maskA[node];
  float u0 = 0.f, u1 = 0.f, u2 = 0.f, u3 = 0.f;
  if (act) {
    float inv = has ? 1.f / rs : 0.f;
    ushort4 sv = *(const ushort4*)(srcb + (size_t)node * 200 + cb);
    float v0 = has ? b2f(sv.x) + a0 * inv : 0.f;
    float v1 = has ? b2f(sv.y) + a1 * inv : 0.f;
    float v2 = has ? b2f(sv.z) + a2v * inv : 0.f;
    float v3 = has ? b2f(sv.w) + a3 * inv : 0.f;
    v0 = (v0 > 0.f) ? v0 : expm1f(v0);
    v1 = (v1 > 0.f) ? v1 : expm1f(v1);
    v2 = (v2 > 0.f) ? v2 : expm1f(v2);
    v3 = (v3 > 0.f) ? v3 : expm1f(v3);
    ushort4 xv = *(const ushort4*)(xwb + (size_t)node * 200 + cb);
    u0 = b2f(xv.x) + m * v0;
    u1 = b2f(xv.y) + m * v1;
    u2 = b2f(xv.z) + m * v2;
    u3 = b2f(xv.w) + m * v3;
  }
  float ss = u0 * u0 + u1 * u1 + u2 * u2 + u3 * u3;
  #pragma unroll
  for (int off = 1; off < 64; off <<= 1) ss += __shfl_xor(ss, off);
  float inv = 1.f / fmaxf(sqrtf(ss), 1e-12f);
  if (act) {
    float4 ov = {u0 * inv, u1 * inv, u2 * inv, u3 * inv};
    *(float4*)(out + (size_t)node * 200 + cb) = ov;
  }
}

extern "C" void kernel_launch(void* const* d_in, const int* in_sizes, int n_in,
                              void* d_out, int out_size, void* d_ws, size_t ws_size,
                              hipStream_t stream) {
  (void)in_sizes; (void)n_in; (void)out_size; (void)ws_size;
  const float* ent      = (const float*)d_in[0];
  const float* rel      = (const float*)d_in[1];
  const float* a_heads  = (const float*)d_in[3];
  const float* a2_heads = (const float*)d_in[4];
  const float* W_gat    = (const float*)d_in[5];
  const float* a_out    = (const float*)d_in[6];
  const float* a2_out   = (const float*)d_in[7];
  const float* W_ent    = (const float*)d_in[8];
  const int* edge_list  = (const int*)d_in[9];
  const int* edge_type  = (const int*)d_in[10];
  const int* tin        = (const int*)d_in[11];
  const int* binp       = (const int*)d_in[12];

  float* out    = (float*)d_out;
  float* outrel = out + 10000000;     // (500,200) output 1

  float* ws = (float*)d_ws;
  unsigned short* bufSb  = (unsigned short*)ws;                // NN*200 bf16
  unsigned short* dstD   = (unsigned short*)(ws + 5000000);
  unsigned short* relp1b = (unsigned short*)(ws + 10000000);
  unsigned short* relp2b = (unsigned short*)(ws + 10050000);
  float* ssrc1 = ws + 10100000;
  float* sdst1 = ws + 10200000;
  float* s2src = ws + 10300000;
  float* s2dst = ws + 10350000;
  float* srel1 = ws + 10400000;
  float* s2rel = ws + 10402000;
  // ---- contiguous zero region ----
  float* maskA = ws + 10404000;                                 // 50k f32
  int*   deg   = (int*)(ws + 10454000);                         // 50k int
  int*   cnts  = (int*)(ws + 10504000);                         // 8 int
  unsigned short* orelb = (unsigned short*)(ws + 10504008);     // 512*224 ushort
  // zero region ends at ws + 10561352
  unsigned short* x0nbf = (unsigned short*)(ws + 10570000);     // MP*128
  unsigned short* xbf   = (unsigned short*)(ws + 13780000);     // MP*224
  unsigned short* B1s   = (unsigned short*)(ws + 19390000);
  unsigned short* B1d   = (unsigned short*)(ws + 19405000);
  unsigned short* Brel1 = (unsigned short*)(ws + 19420000);
  unsigned short* Bxw   = (unsigned short*)(ws + 19435000);
  unsigned short* Bwgat = (unsigned short*)(ws + 19450000);
  unsigned short* B2s   = (unsigned short*)(ws + 19465000);
  unsigned short* B2d   = (unsigned short*)(ws + 19490000);
  unsigned short* B2rel = (unsigned short*)(ws + 19515000);
  unsigned short* relbf = (unsigned short*)(ws + 19540000);     // 512*128
  float2* eeb1 = (float2*)(ws + 19580000);                      // ETOT float2
  float*  eeb2 = ws + 20330000;                                 // ETOT float
  unsigned short* xwb = (unsigned short*)(ws + 20710000);       // NN*200 bf16
  int* ibase  = (int*)(ws + 25710000);
  int* offs   = ibase;                 // 50k+1
  int* pos    = ibase + 50016;
  int* bsum   = ibase + 100016;        // 256
  int* lightL = ibase + 100288;
  int* heavyL = ibase + 150288;
  int2* edata = (int2*)(ibase + 200288);

  hipMemsetAsync(maskA, 0, (size_t)(10561352 - 10404000) * 4, stream);

  // l2norm + histk + weight conversions
  {
    dim3 g(12512, 3);
    startk<<<g, 256, 0, stream>>>(ent, x0nbf, edge_list, tin, deg,
                                  rel, a_heads, W_ent, W_gat, a_out,
                                  B1s, B1d, Brel1, Bxw, Bwgat, B2s, B2d, B2rel, relbf);
  }
  scanA<<<196, 256, 0, stream>>>(deg, bsum, NN);
  scanC<<<196, 256, 0, stream>>>(deg, bsum, offs, pos, NN, ETOT);
  {
    dim3 g(1465, 2);
    scatBuild<<<g, 256, 0, stream>>>(edge_list, edge_type, tin, offs, pos, edata,
                                     lightL, heavyL, cnts);
  }

  // layer-1 projections + xw(bf16) + rel projections + out_relation_1, one 5-job launch
  {
    GJob js    = {x0nbf, NN,    B1s,   nullptr, bufSb,  200, a2_heads, ssrc1, 1};
    GJob jd    = {x0nbf, NN,    B1d,   nullptr, dstD,   200, a2_heads, sdst1, 1};
    GJob jx    = {x0nbf, NN,    Bxw,   nullptr, xwb,    200, nullptr,  nullptr, 0};
    GJob jrel1 = {relbf, NRELS, Brel1, nullptr, relp1b, 200, a2_heads, srel1, 1};
    GJob jorel = {relbf, NRELS, Bwgat, outrel,  orelb,  224, nullptr,  nullptr, 0};
    dim3 g(782, 5);
    gemm_multi<128><<<g, 256, 0, stream>>>(js, jd, jx, jrel1, jorel);
  }

  // edgeEE1 + padx + maskset
  {
    dim3 g(1465, 2);
    eeMisc1<<<g, 256, 0, stream>>>(edata, ssrc1, sdst1, srel1, eeb1, xbf, binp, maskA);
  }

  gather1M<<<HBMAX + LB1, 512, 0, stream>>>(lightL, heavyL, cnts, offs, edata, eeb1,
                                            bufSb, dstD, relp1b, xbf);

  // layer-2 projections + relp2, one 3-job launch
  {
    GJob js    = {xbf,   NN,    B2s,   nullptr, bufSb,  200, a2_out, s2src, 2};
    GJob jd    = {xbf,   NN,    B2d,   nullptr, dstD,   200, a2_out, s2dst, 2};
    GJob jrp2  = {orelb, NRELS, B2rel, nullptr, relp2b, 200, a2_out, s2rel, 2};
    GJob jz    = {nullptr, 0, nullptr, nullptr, nullptr, 0, nullptr, nullptr, 0};
    dim3 g(782, 3);
    gemm_multi<224><<<g, 256, 0, stream>>>(js, jd, jrp2, jz, jz);
  }

  edgeEE2<<<(ETOT + 255) / 256, 256, 0, stream>>>(edata, s2src, s2dst, s2rel, eeb2);

  // gather2 with fused elu+mask+l2norm epilogue -> out
  gather2M<<<HBMAX + LB1, 512, 0, stream>>>(lightL, heavyL, cnts, offs, edata, eeb2,
                                            bufSb, dstD, relp2b, xwb, maskA, out);
}